// Round 12
// baseline (1555.601 us; speedup 1.0000x reference)
//
#include <hip/hip_runtime.h>
#include <hip/hip_bf16.h>
#include <cstdint>
#include <cstddef>

// Shapes: B=64, T=512, J=64, D=256, E=128, gdim=8E=1024, gates=4E=512
// ws layout (bytes), total 137,371,648 (~131 MiB):
//   [0,           67,108,864)  g bf16 (32768 x 1024)   -- dead after gemm1
//        aliased: m  bf16 (32768 x 256) at 0 ; m2 bf16 at 33,554,432
//   [67,108,864, 100,663,296)  pre_f bf16 (32768 x 512)  [cell][gate] layout
//   [100,663,296,134,217,728)  pre_b bf16 (32768 x 512)  [cell][gate] layout
//   [134,217,728,134,742,016)  gz0, gz1, smax, z (32768 fp32 each)
//   [134,742,016,135,790,592)  w1f bf16 (512x1024)
//   [135,790,592,136,839,168)  w1b bf16
//   [136,839,168,137,101,312)  w2f bf16 (512x256)
//   [137,101,312,137,363,456)  w2b bf16
//   [137,363,456,137,371,648)  bs[4][512] fp32 (bih+bhh, l1f/l1b/l2f/l2b)

typedef short short8v __attribute__((ext_vector_type(8)));
typedef float f32x4 __attribute__((ext_vector_type(4)));
typedef unsigned short ushort8v __attribute__((ext_vector_type(8)));
typedef unsigned short ushort4v __attribute__((ext_vector_type(4)));

static __device__ __forceinline__ float bf2f(unsigned short u) {
  return __uint_as_float(((unsigned int)u) << 16);
}
static __device__ __forceinline__ unsigned short f2bf(float f) {  // RNE
  unsigned int u = __float_as_uint(f);
  return (unsigned short)((u + 0x7FFFu + ((u >> 16) & 1u)) >> 16);
}
static __device__ __forceinline__ float fsig(float x) {
  return 1.f / (1.f + __expf(-x));
}
static __device__ __forceinline__ float ftanh(float x) {
  return 1.f - 2.f / (__expf(2.f * x) + 1.f);
}

// ---------------- weight pre-convert: 4x Wih fp32->bf16, bias sums ----------
__global__ __launch_bounds__(256) void cvt_w_kernel(
    const float* __restrict__ w1f, const float* __restrict__ w1b,
    const float* __restrict__ w2f, const float* __restrict__ w2b,
    const float* __restrict__ b1fi, const float* __restrict__ b1fh,
    const float* __restrict__ b1bi, const float* __restrict__ b1bh,
    const float* __restrict__ b2fi, const float* __restrict__ b2fh,
    const float* __restrict__ b2bi, const float* __restrict__ b2bh,
    unsigned short* __restrict__ d1f, unsigned short* __restrict__ d1b,
    unsigned short* __restrict__ d2f, unsigned short* __restrict__ d2b,
    float* __restrict__ bs)
{
  const int bid = blockIdx.x, tid = threadIdx.x;
  if (bid < 1280) {
    int idx = (bid * 256 + tid) * 4;
    const float* src;
    unsigned short* dst;
    int off;
    if (idx < 524288)        { src = w1f; dst = d1f; off = idx; }
    else if (idx < 1048576)  { src = w1b; dst = d1b; off = idx - 524288; }
    else if (idx < 1179648)  { src = w2f; dst = d2f; off = idx - 1048576; }
    else                     { src = w2b; dst = d2b; off = idx - 1179648; }
    float4 f = *(const float4*)(src + off);
    ushort4v v;
    v[0] = f2bf(f.x); v[1] = f2bf(f.y); v[2] = f2bf(f.z); v[3] = f2bf(f.w);
    *(ushort4v*)(dst + off) = v;
  } else {
    int bidx = (bid - 1280) * 256 + tid;   // 0..2047
    int which = bidx >> 9, col = bidx & 511;
    float v;
    if (which == 0)      v = b1fi[col] + b1fh[col];
    else if (which == 1) v = b1bi[col] + b1bh[col];
    else if (which == 2) v = b2fi[col] + b2fh[col];
    else                 v = b2bi[col] + b2bh[col];
    bs[bidx] = v;
  }
}

// ---------------- MFMA attention (r11 winner) ----------------
__global__ __launch_bounds__(256) void attn_kernel(
    const float* __restrict__ c, const float* __restrict__ q,
    const float* __restrict__ wc, const float* __restrict__ bc,
    const float* __restrict__ wq, const float* __restrict__ bq,
    const float* __restrict__ wcq, const float* __restrict__ bcq,
    const float* __restrict__ W0, const float* __restrict__ W1,
    __hip_bfloat16* __restrict__ g, float* __restrict__ smax,
    float* __restrict__ gz0, float* __restrict__ gz1)
{
  __shared__ unsigned short cbf[128][264];  // c bf16 (A for S; cv in epilogue)
  __shared__ unsigned short qhb[64][264];   // qhat bf16 j-major (B for S)
  __shared__ unsigned short qtb[256][72];   // q bf16 d-major (B for c2q)
  __shared__ unsigned short Pbuf[4][16][72];// per-wave P transpose (A for c2q)
  __shared__ float qwqs[64];
  __shared__ float qwp[4][64];
  const int b = blockIdx.x, tid = threadIdx.x;
  const int wave = tid >> 6, lane = tid & 63;
  const int t0 = blockIdx.y * 128;
  unsigned short* gbase = (unsigned short*)g;

  #pragma unroll
  for (int i = 0; i < 16; ++i) {
    int idx = tid + i * 256;               // 4096 float4
    int j = idx >> 6, d4 = (idx & 63) * 4;
    float4 v = *(const float4*)&q[((size_t)b * 64 + j) * 256 + d4];
    float4 w4 = *(const float4*)&wcq[d4];
    float4 c4 = *(const float4*)&wc[d4];
    qhb[j][d4 + 0] = f2bf(v.x * w4.x + c4.x);
    qhb[j][d4 + 1] = f2bf(v.y * w4.y + c4.y);
    qhb[j][d4 + 2] = f2bf(v.z * w4.z + c4.z);
    qhb[j][d4 + 3] = f2bf(v.w * w4.w + c4.w);
    qtb[d4 + 0][j] = f2bf(v.x);
    qtb[d4 + 1][j] = f2bf(v.y);
    qtb[d4 + 2][j] = f2bf(v.z);
    qtb[d4 + 3][j] = f2bf(v.w);
  }
  #pragma unroll
  for (int i = 0; i < 32; ++i) {
    int idx = tid + i * 256;               // 8192 float4
    int r = idx >> 6, d4 = (idx & 63) * 4;
    float4 v = *(const float4*)&c[((size_t)b * 512 + t0 + r) * 256 + d4];
    ushort4v u;
    u[0] = f2bf(v.x); u[1] = f2bf(v.y); u[2] = f2bf(v.z); u[3] = f2bf(v.w);
    *(ushort4v*)&cbf[r][d4] = u;
    *(ushort4v*)&gbase[((size_t)b * 512 + t0 + r) * 1024 + d4] = u;
  }
  __syncthreads();
  {
    float s = 0.f;
    for (int dd = 0; dd < 64; ++dd) {
      int d = wave * 64 + dd;
      s += bf2f(qtb[d][lane]) * wq[d];
    }
    qwp[wave][lane] = s;
  }
  __syncthreads();
  if (tid < 64) qwqs[tid] = qwp[0][tid] + qwp[1][tid] + qwp[2][tid] + qwp[3][tid] + bq[0];
  __syncthreads();

  const int cl = lane & 15, kg = lane >> 4;
  const float sbias = bc[0] + bcq[0];

  #pragma unroll
  for (int half = 0; half < 2; ++half) {
    const int tt = wave + half * 4;
    const int rowb = tt * 16;
    f32x4 acc[4] = {};
    #pragma unroll
    for (int kt = 0; kt < 8; ++kt) {
      short8v a = *(const short8v*)&cbf[rowb + cl][kt * 32 + kg * 8];
      #pragma unroll
      for (int jt = 0; jt < 4; ++jt) {
        short8v bq_ = *(const short8v*)&qhb[jt * 16 + cl][kt * 32 + kg * 8];
        acc[jt] = __builtin_amdgcn_mfma_f32_16x16x32_bf16(a, bq_, acc[jt], 0, 0, 0);
      }
    }
    #pragma unroll
    for (int jt = 0; jt < 4; ++jt) {
      float qadd = qwqs[jt * 16 + cl] + sbias;
      #pragma unroll
      for (int r = 0; r < 4; ++r) acc[jt][r] += qadd;
    }
    f32x4 mx = acc[0];
    #pragma unroll
    for (int jt = 1; jt < 4; ++jt)
      #pragma unroll
      for (int r = 0; r < 4; ++r) mx[r] = fmaxf(mx[r], acc[jt][r]);
    #pragma unroll
    for (int off = 1; off < 16; off <<= 1)
      #pragma unroll
      for (int r = 0; r < 4; ++r) mx[r] = fmaxf(mx[r], __shfl_xor(mx[r], off));
    f32x4 se = {0.f, 0.f, 0.f, 0.f};
    #pragma unroll
    for (int jt = 0; jt < 4; ++jt)
      #pragma unroll
      for (int r = 0; r < 4; ++r) {
        acc[jt][r] = __expf(acc[jt][r] - mx[r]);
        se[r] += acc[jt][r];
      }
    #pragma unroll
    for (int off = 1; off < 16; off <<= 1)
      #pragma unroll
      for (int r = 0; r < 4; ++r) se[r] += __shfl_xor(se[r], off);
    f32x4 inv;
    #pragma unroll
    for (int r = 0; r < 4; ++r) inv[r] = 1.f / se[r];
    #pragma unroll
    for (int jt = 0; jt < 4; ++jt)
      #pragma unroll
      for (int r = 0; r < 4; ++r)
        Pbuf[wave][4 * kg + r][jt * 16 + cl] = f2bf(acc[jt][r] * inv[r]);
    if (cl == 0) {
      #pragma unroll
      for (int r = 0; r < 4; ++r)
        smax[(size_t)b * 512 + t0 + rowb + 4 * kg + r] = mx[r];
    }
    f32x4 gz0p = {0.f, 0.f, 0.f, 0.f}, gz1p = {0.f, 0.f, 0.f, 0.f};
    for (int dt = 0; dt < 16; ++dt) {
      f32x4 ca = {0.f, 0.f, 0.f, 0.f};
      #pragma unroll
      for (int kt = 0; kt < 2; ++kt) {
        short8v pa = *(const short8v*)&Pbuf[wave][cl][kt * 32 + kg * 8];
        short8v qb_ = *(const short8v*)&qtb[dt * 16 + cl][kt * 32 + kg * 8];
        ca = __builtin_amdgcn_mfma_f32_16x16x32_bf16(pa, qb_, ca, 0, 0, 0);
      }
      int d = dt * 16 + cl;
      float w0a = W0[d], w0b_ = W0[256 + d], w0c2 = W0[512 + d];
      float w1a = W1[d], w1b2 = W1[256 + d], w1c2 = W1[512 + d];
      #pragma unroll
      for (int r = 0; r < 4; ++r) {
        int rloc = rowb + 4 * kg + r;
        float cv = bf2f(cbf[rloc][d]);
        float av = ca[r];
        float pr = cv * av;
        size_t gr = ((size_t)b * 512 + t0 + rloc) * 1024;
        gbase[gr + 256 + d] = f2bf(av);
        gbase[gr + 512 + d] = f2bf(pr);
        gz0p[r] += cv * w0a + av * w0b_ + pr * w0c2;
        gz1p[r] += cv * w1a + av * w1b2 + pr * w1c2;
      }
    }
    #pragma unroll
    for (int off = 1; off < 16; off <<= 1)
      #pragma unroll
      for (int r = 0; r < 4; ++r) {
        gz0p[r] += __shfl_xor(gz0p[r], off);
        gz1p[r] += __shfl_xor(gz1p[r], off);
      }
    if (cl == 0) {
      #pragma unroll
      for (int r = 0; r < 4; ++r) {
        size_t rw = (size_t)b * 512 + t0 + rowb + 4 * kg + r;
        gz0[rw] = gz0p[r];
        gz1[rw] = gz1p[r];
      }
    }
  }
}

// ---------------- b_att softmax over t, q2c, g[768:1024] bf16, gz tail ----------
__global__ __launch_bounds__(256) void batt_kernel(
    const float* __restrict__ c, const float* __restrict__ smax,
    const float* __restrict__ W0, const float* __restrict__ W1,
    __hip_bfloat16* __restrict__ g,
    float* __restrict__ gz0, float* __restrict__ gz1)
{
  __shared__ float sm[512];
  __shared__ float red[4], red2[4];
  __shared__ float q2c_s[256];
  const int b = blockIdx.x, tid = threadIdx.x;
  float v0 = smax[(size_t)b * 512 + tid];
  float v1 = smax[(size_t)b * 512 + tid + 256];
  float m = fmaxf(v0, v1);
  #pragma unroll
  for (int off = 32; off; off >>= 1) m = fmaxf(m, __shfl_xor(m, off));
  if ((tid & 63) == 0) red[tid >> 6] = m;
  __syncthreads();
  float M = fmaxf(fmaxf(red[0], red[1]), fmaxf(red[2], red[3]));
  float e0 = expf(v0 - M), e1 = expf(v1 - M);
  float ssum = e0 + e1;
  #pragma unroll
  for (int off = 32; off; off >>= 1) ssum += __shfl_xor(ssum, off);
  if ((tid & 63) == 0) red2[tid >> 6] = ssum;
  __syncthreads();
  float S = red2[0] + red2[1] + red2[2] + red2[3];
  sm[tid] = e0 / S;
  sm[tid + 256] = e1 / S;
  __syncthreads();
  float acc = 0.f;
  #pragma unroll 8
  for (int t = 0; t < 512; ++t) acc += sm[t] * c[((size_t)b * 512 + t) * 256 + tid];
  q2c_s[tid] = acc;
  __syncthreads();
  const int wave = tid >> 6, lane = tid & 63;
  float qv[4], w0c[4], w1c[4];
  #pragma unroll
  for (int r = 0; r < 4; ++r) {
    int d = lane + 64 * r;
    qv[r]  = q2c_s[d];
    w0c[r] = W0[768 + d];
    w1c[r] = W1[768 + d];
  }
  for (int t = wave; t < 512; t += 4) {
    size_t row = (size_t)b * 512 + t;
    float s0 = 0.f, s1 = 0.f;
    #pragma unroll
    for (int r = 0; r < 4; ++r) {
      int d = lane + 64 * r;
      float v = c[row * 256 + d];
      float gv = v * qv[r];
      g[row * 1024 + 768 + d] = __float2bfloat16(gv);
      s0 += gv * w0c[r];
      s1 += gv * w1c[r];
    }
    #pragma unroll
    for (int off = 32; off; off >>= 1) {
      s0 += __shfl_xor(s0, off);
      s1 += __shfl_xor(s1, off);
    }
    if (lane == 0) { gz0[row] += s0; gz1[row] += s1; }
  }
}

// ---------------- MFMA GEMM: pre[M,512] = Xbf16[M,K] @ Wbf16[512,K]^T + bs ------
__global__ __launch_bounds__(256) void gemm_mfma_kernel(
    const __hip_bfloat16* __restrict__ Xg,
    const unsigned short* __restrict__ Wf, const unsigned short* __restrict__ Wb,
    const float* __restrict__ bsf, const float* __restrict__ bsb,
    __hip_bfloat16* __restrict__ Yf, __hip_bfloat16* __restrict__ Yb, int K)
{
  __shared__ unsigned short Xs[128 * 72];
  __shared__ unsigned short Ws[128 * 72];
  const unsigned short* X = (const unsigned short*)Xg;
  const unsigned short* W = blockIdx.z ? Wb : Wf;
  const float* bs = blockIdx.z ? bsb : bsf;
  __hip_bfloat16* Y = blockIdx.z ? Yb : Yf;
  const int tid = threadIdx.x;
  const int m0 = blockIdx.x * 128, n0 = blockIdx.y * 128;
  const int lane = tid & 63, wave = tid >> 6;
  const int wr = wave >> 1, wc = wave & 1;
  const int frow = lane & 15, fk = (lane >> 4) * 8;

  f32x4 acc[4][4] = {};
  for (int kt = 0; kt < K; kt += 64) {
    #pragma unroll
    for (int i = 0; i < 4; ++i) {
      int cidx = tid + 256 * i;          // 0..1023
      int row = cidx >> 3, kc = cidx & 7;
      *(ushort8v*)&Xs[row * 72 + kc * 8] =
          *(const ushort8v*)&X[(size_t)(m0 + row) * K + kt + kc * 8];
      *(ushort8v*)&Ws[row * 72 + kc * 8] =
          *(const ushort8v*)&W[(size_t)(n0 + row) * K + kt + kc * 8];
    }
    __syncthreads();
    #pragma unroll
    for (int kk = 0; kk < 64; kk += 32) {
      short8v a[4], bfr[4];
      #pragma unroll
      for (int i = 0; i < 4; ++i)
        a[i] = *(const short8v*)&Xs[(wr * 64 + i * 16 + frow) * 72 + kk + fk];
      #pragma unroll
      for (int j = 0; j < 4; ++j)
        bfr[j] = *(const short8v*)&Ws[(wc * 64 + j * 16 + frow) * 72 + kk + fk];
      #pragma unroll
      for (int i = 0; i < 4; ++i)
        #pragma unroll
        for (int j = 0; j < 4; ++j)
          acc[i][j] = __builtin_amdgcn_mfma_f32_16x16x32_bf16(a[i], bfr[j], acc[i][j], 0, 0, 0);
    }
    __syncthreads();
  }
  const int r0 = (lane >> 4) * 4;
  #pragma unroll
  for (int j = 0; j < 4; ++j) {
    int col = n0 + wc * 64 + j * 16 + (lane & 15);
    int colp = (col & 127) * 4 + (col >> 7);   // [cell][gate] permuted layout
    float bsum = bs[col];
    #pragma unroll
    for (int i = 0; i < 4; ++i) {
      int rowb = m0 + wr * 64 + i * 16 + r0;
      #pragma unroll
      for (int r = 0; r < 4; ++r)
        Y[(size_t)(rowb + r) * 512 + colp] = __float2bfloat16(acc[i][j][r] + bsum);
    }
  }
}

// ---------------- LSTM recurrence via MFMA, 16 waves (4/SIMD) ----------------
// grid (64, 2) block 1024. Wave w owns cells 8w..8w+7 (gate-rows 32w..32w+31,
// [cell][gate] layout) as 2 N-tiles of 16. Per wave per step: 4 ds_read_b128
// (h bcast) + 8 MFMA (2 indep depth-4 chains) + own-gate activation +
// 4-lane shfl gather + cst tail. 4 waves/SIMD hide each other's chains
// (r8's 2 waves/SIMD left step at 1530cy vs the 620cy MFMA-issue floor).
// VMEM chunked over 8 steps. Whh cvt fp32->bf16 in-kernel (defeats remat), pinned.
__global__ __launch_bounds__(1024) void lstm_kernel(
    const __hip_bfloat16* __restrict__ pre_f, const __hip_bfloat16* __restrict__ pre_b,
    const float* __restrict__ Whh_f, const float* __restrict__ Whh_b,
    __hip_bfloat16* __restrict__ out)
{
  const int b = blockIdx.x, dir = blockIdx.y;
  const unsigned short* __restrict__ pre =
      (const unsigned short*)(dir ? pre_b : pre_f);
  const float* __restrict__ Whh = dir ? Whh_b : Whh_f;
  const int off = dir ? 128 : 0;
  const int tid = threadIdx.x;
  const int wave = tid >> 6, lane = tid & 63;
  const int cl = lane & 15;            // col within N-tile
  const int kg = lane >> 4;            // k-group 0..3
  const int q3 = cl & 3;               // gate of this lane's rows
  const int lbase = lane & ~3;         // first lane of the 4-gate group
  const int cellA = 8 * wave + (cl >> 2);   // tile-0 cell
  const int cellB = cellA + 4;              // tile-1 cell
  const int nA = 32 * wave + cl;            // tile-0 gate-row (permuted n)
  const int nB = nA + 16;                   // tile-1 gate-row

  // B frags: b<T><K> = Whh_orig[(n&3)*128 + (n>>2)][K*32 + kg*8 .. +8] as bf16
#define LOAD_BF(N, KT, DST)                                                 \
  {                                                                         \
    const float* wp = Whh + (size_t)(((N) & 3) * 128 + ((N) >> 2)) * 128 +  \
                      (KT) * 32 + kg * 8;                                   \
    float4 f0 = *(const float4*)wp;                                         \
    float4 f1 = *(const float4*)(wp + 4);                                   \
    DST[0] = (short)f2bf(f0.x); DST[1] = (short)f2bf(f0.y);                 \
    DST[2] = (short)f2bf(f0.z); DST[3] = (short)f2bf(f0.w);                 \
    DST[4] = (short)f2bf(f1.x); DST[5] = (short)f2bf(f1.y);                 \
    DST[6] = (short)f2bf(f1.z); DST[7] = (short)f2bf(f1.w);                 \
    asm volatile("" : "+v"(DST));                                           \
  }
  short8v b00, b01, b02, b03, b10, b11, b12, b13;
  LOAD_BF(nA, 0, b00) LOAD_BF(nA, 1, b01) LOAD_BF(nA, 2, b02) LOAD_BF(nA, 3, b03)
  LOAD_BF(nB, 0, b10) LOAD_BF(nB, 1, b11) LOAD_BF(nB, 2, b12) LOAD_BF(nB, 3, b13)
#undef LOAD_BF

  __shared__ unsigned short hbuf[2][128];
  if (tid < 128) { hbuf[0][tid] = 0; hbuf[1][tid] = 0; }
  __syncthreads();

  const size_t base = (size_t)b * 512;
  const int tstep = dir ? -1 : 1;
  const int t0 = dir ? 511 : 0;
  const unsigned short* prowA = pre + base * 512 + nA;     // + t*512
  const unsigned short* prowB = pre + base * 512 + nB;
  unsigned short* orowA = (unsigned short*)out + base * 256 + off + cellA;
  unsigned short* orowB = (unsigned short*)out + base * 256 + off + cellB;
  const bool writer = (kg == 0) && (q3 == 0);

  int cur = 0;
  float cstA = 0.f, cstB = 0.f;
  f32x4 acc0 = {0.f, 0.f, 0.f, 0.f};
  f32x4 acc1 = acc0;

#define LSTM_STEP(PA, PB, HA, HB)                                           \
  {                                                                         \
    const unsigned short* hb = hbuf[cur];                                   \
    short8v a0 = *(const short8v*)(hb +  0 + kg * 8);                       \
    short8v a1 = *(const short8v*)(hb + 32 + kg * 8);                       \
    short8v a2 = *(const short8v*)(hb + 64 + kg * 8);                       \
    short8v a3 = *(const short8v*)(hb + 96 + kg * 8);                       \
    acc0[0] = bf2f(PA); acc1[0] = bf2f(PB);                                 \
    acc0 = __builtin_amdgcn_mfma_f32_16x16x32_bf16(a0, b00, acc0, 0, 0, 0); \
    acc1 = __builtin_amdgcn_mfma_f32_16x16x32_bf16(a0, b10, acc1, 0, 0, 0); \
    acc0 = __builtin_amdgcn_mfma_f32_16x16x32_bf16(a1, b01, acc0, 0, 0, 0); \
    acc1 = __builtin_amdgcn_mfma_f32_16x16x32_bf16(a1, b11, acc1, 0, 0, 0); \
    acc0 = __builtin_amdgcn_mfma_f32_16x16x32_bf16(a2, b02, acc0, 0, 0, 0); \
    acc1 = __builtin_amdgcn_mfma_f32_16x16x32_bf16(a2, b12, acc1, 0, 0, 0); \
    acc0 = __builtin_amdgcn_mfma_f32_16x16x32_bf16(a3, b03, acc0, 0, 0, 0); \
    acc1 = __builtin_amdgcn_mfma_f32_16x16x32_bf16(a3, b13, acc1, 0, 0, 0); \
    float x0 = acc0[0], x1 = acc1[0];                                       \
    float av0 = (q3 == 2) ? ftanh(x0) : fsig(x0);                           \
    float av1 = (q3 == 2) ? ftanh(x1) : fsig(x1);                           \
    float gi0 = __shfl(av0, lbase),     gf0 = __shfl(av0, lbase + 1);       \
    float gg0 = __shfl(av0, lbase + 2), go0 = __shfl(av0, lbase + 3);       \
    float gi1 = __shfl(av1, lbase),     gf1 = __shfl(av1, lbase + 1);       \
    float gg1 = __shfl(av1, lbase + 2), go1 = __shfl(av1, lbase + 3);       \
    cstA = gf0 * cstA + gi0 * gg0;                                          \
    cstB = gf1 * cstB + gi1 * gg1;                                          \
    float hv0 = go0 * ftanh(cstA);                                          \
    float hv1 = go1 * ftanh(cstB);                                          \
    HA = f2bf(hv0); HB = f2bf(hv1);                                         \
    if (writer) {                                                           \
      hbuf[cur ^ 1][cellA] = HA;                                            \
      hbuf[cur ^ 1][cellB] = HB;                                            \
    }                                                                       \
    __syncthreads();                                                        \
    cur ^= 1;                                                               \
  }

  for (int chunk = 0; chunk < 64; ++chunk) {
    const int tb = t0 + chunk * 8 * tstep;
    unsigned short pa0 = prowA[(size_t)(tb)             * 512];
    unsigned short pb0 = prowB[(size_t)(tb)             * 512];
    unsigned short pa1 = prowA[(size_t)(tb + 1 * tstep) * 512];
    unsigned short pb1 = prowB[(size_t)(tb + 1 * tstep) * 512];
    unsigned short pa2 = prowA[(size_t)(tb + 2 * tstep) * 512];
    unsigned short pb2 = prowB[(size_t)(tb + 2 * tstep) * 512];
    unsigned short pa3 = prowA[(size_t)(tb + 3 * tstep) * 512];
    unsigned short pb3 = prowB[(size_t)(tb + 3 * tstep) * 512];
    unsigned short pa4 = prowA[(size_t)(tb + 4 * tstep) * 512];
    unsigned short pb4 = prowB[(size_t)(tb + 4 * tstep) * 512];
    unsigned short pa5 = prowA[(size_t)(tb + 5 * tstep) * 512];
    unsigned short pb5 = prowB[(size_t)(tb + 5 * tstep) * 512];
    unsigned short pa6 = prowA[(size_t)(tb + 6 * tstep) * 512];
    unsigned short pb6 = prowB[(size_t)(tb + 6 * tstep) * 512];
    unsigned short pa7 = prowA[(size_t)(tb + 7 * tstep) * 512];
    unsigned short pb7 = prowB[(size_t)(tb + 7 * tstep) * 512];
    unsigned short hA0, hA1, hA2, hA3, hA4, hA5, hA6, hA7;
    unsigned short hB0, hB1, hB2, hB3, hB4, hB5, hB6, hB7;
    LSTM_STEP(pa0, pb0, hA0, hB0)
    LSTM_STEP(pa1, pb1, hA1, hB1)
    LSTM_STEP(pa2, pb2, hA2, hB2)
    LSTM_STEP(pa3, pb3, hA3, hB3)
    LSTM_STEP(pa4, pb4, hA4, hB4)
    LSTM_STEP(pa5, pb5, hA5, hB5)
    LSTM_STEP(pa6, pb6, hA6, hB6)
    LSTM_STEP(pa7, pb7, hA7, hB7)
    if (writer) {
      orowA[(size_t)(tb)             * 256] = hA0;
      orowA[(size_t)(tb + 1 * tstep) * 256] = hA1;
      orowA[(size_t)(tb + 2 * tstep) * 256] = hA2;
      orowA[(size_t)(tb + 3 * tstep) * 256] = hA3;
      orowA[(size_t)(tb + 4 * tstep) * 256] = hA4;
      orowA[(size_t)(tb + 5 * tstep) * 256] = hA5;
      orowA[(size_t)(tb + 6 * tstep) * 256] = hA6;
      orowA[(size_t)(tb + 7 * tstep) * 256] = hA7;
      orowB[(size_t)(tb)             * 256] = hB0;
      orowB[(size_t)(tb + 1 * tstep) * 256] = hB1;
      orowB[(size_t)(tb + 2 * tstep) * 256] = hB2;
      orowB[(size_t)(tb + 3 * tstep) * 256] = hB3;
      orowB[(size_t)(tb + 4 * tstep) * 256] = hB4;
      orowB[(size_t)(tb + 5 * tstep) * 256] = hB5;
      orowB[(size_t)(tb + 6 * tstep) * 256] = hB6;
      orowB[(size_t)(tb + 7 * tstep) * 256] = hB7;
    }
  }
#undef LSTM_STEP
}

// ---------------- logits: z[row] = gz[row] + m_row(bf16) . W[1024:1280] + bias ----
__global__ __launch_bounds__(256) void logits_kernel(
    const __hip_bfloat16* __restrict__ m, const float* __restrict__ W,
    const float* __restrict__ bias, const float* __restrict__ gz,
    float* __restrict__ z)
{
  const int row = blockIdx.x * 4 + (threadIdx.x >> 6);
  const int lane = threadIdx.x & 63;
  const unsigned short* mrow = (const unsigned short*)m + (size_t)row * 256;
  float acc = 0.f;
  #pragma unroll
  for (int i = 0; i < 4; ++i) acc += bf2f(mrow[lane + 64 * i]) * W[1024 + lane + 64 * i];
  #pragma unroll
  for (int off = 32; off; off >>= 1) acc += __shfl_xor(acc, off);
  if (lane == 0) z[row] = acc + gz[row] + bias[0];
}

// ---------------- softmax over t ----------------
__global__ __launch_bounds__(512) void softmax_t_kernel(
    const float* __restrict__ z, float* __restrict__ p)
{
  const int b = blockIdx.x, t = threadIdx.x;
  __shared__ float red[8], red2[8];
  float v = z[(size_t)b * 512 + t];
  float m = v;
  #pragma unroll
  for (int off = 32; off; off >>= 1) m = fmaxf(m, __shfl_xor(m, off));
  if ((t & 63) == 0) red[t >> 6] = m;
  __syncthreads();
  float M = red[0];
  #pragma unroll
  for (int i = 1; i < 8; ++i) M = fmaxf(M, red[i]);
  float e = expf(v - M);
  float s = e;
  #pragma unroll
  for (int off = 32; off; off >>= 1) s += __shfl_xor(s, off);
  if ((t & 63) == 0) red2[t >> 6] = s;
  __syncthreads();
  float S = red2[0];
  #pragma unroll
  for (int i = 1; i < 8; ++i) S += red2[i];
  p[(size_t)b * 512 + t] = e / S;
}

extern "C" void kernel_launch(void* const* d_in, const int* in_sizes, int n_in,
                              void* d_out, int out_size, void* d_ws, size_t ws_size,
                              hipStream_t stream)
{
  const float* c   = (const float*)d_in[0];
  const float* q   = (const float*)d_in[1];
  const float* wc  = (const float*)d_in[2];
  const float* bc  = (const float*)d_in[3];
  const float* wq  = (const float*)d_in[4];
  const float* bq  = (const float*)d_in[5];
  const float* wcq = (const float*)d_in[6];
  const float* bcq = (const float*)d_in[7];
  const float* l1f_Wih = (const float*)d_in[8];
  const float* l1f_Whh = (const float*)d_in[9];
  const float* l1f_bih = (const float*)d_in[10];
  const float* l1f_bhh = (const float*)d_in[11];
  const float* l1b_Wih = (const float*)d_in[12];
  const float* l1b_Whh = (const float*)d_in[13];
  const float* l1b_bih = (const float*)d_in[14];
  const float* l1b_bhh = (const float*)d_in[15];
  const float* l2f_Wih = (const float*)d_in[16];
  const float* l2f_Whh = (const float*)d_in[17];
  const float* l2f_bih = (const float*)d_in[18];
  const float* l2f_bhh = (const float*)d_in[19];
  const float* l2b_Wih = (const float*)d_in[20];
  const float* l2b_Whh = (const float*)d_in[21];
  const float* l2b_bih = (const float*)d_in[22];
  const float* l2b_bhh = (const float*)d_in[23];
  const float* W0 = (const float*)d_in[24];
  const float* b0 = (const float*)d_in[25];
  const float* W1 = (const float*)d_in[26];
  const float* b1 = (const float*)d_in[27];

  const size_t required = 137371648u;
  if (ws_size < required) return;

  char* wsb = (char*)d_ws;
  __hip_bfloat16* gbf = (__hip_bfloat16*)wsb;
  __hip_bfloat16* m   = (__hip_bfloat16*)wsb;
  __hip_bfloat16* m2  = (__hip_bfloat16*)(wsb + 33554432);
  __hip_bfloat16* pref = (__hip_bfloat16*)(wsb + 67108864);
  __hip_bfloat16* preb = (__hip_bfloat16*)(wsb + 100663296);
  float* gz0  = (float*)(wsb + 134217728);
  float* gz1  = gz0 + 32768;
  float* smax = gz1 + 32768;
  float* z    = smax + 32768;
  unsigned short* w1f = (unsigned short*)(wsb + 134742016);
  unsigned short* w1b = (unsigned short*)(wsb + 135790592);
  unsigned short* w2f = (unsigned short*)(wsb + 136839168);
  unsigned short* w2b = (unsigned short*)(wsb + 137101312);
  float* bs = (float*)(wsb + 137363456);
  float* p1 = (float*)d_out;
  float* p2 = p1 + 32768;

  cvt_w_kernel<<<1288, 256, 0, stream>>>(l1f_Wih, l1b_Wih, l2f_Wih, l2b_Wih,
                                         l1f_bih, l1f_bhh, l1b_bih, l1b_bhh,
                                         l2f_bih, l2f_bhh, l2b_bih, l2b_bhh,
                                         w1f, w1b, w2f, w2b, bs);
  attn_kernel<<<dim3(64, 4), 256, 0, stream>>>(c, q, wc, bc, wq, bq, wcq, bcq,
                                               W0, W1, gbf, smax, gz0, gz1);
  batt_kernel<<<64, 256, 0, stream>>>(c, smax, W0, W1, gbf, gz0, gz1);

  gemm_mfma_kernel<<<dim3(256, 4, 2), 256, 0, stream>>>(
      gbf, w1f, w1b, bs, bs + 512, pref, preb, 1024);
  lstm_kernel<<<dim3(64, 2), 1024, 0, stream>>>(pref, preb, l1f_Whh, l1b_Whh, m);

  logits_kernel<<<8192, 256, 0, stream>>>(m, W0, b0, gz0, z);
  softmax_t_kernel<<<64, 512, 0, stream>>>(z, p1);

  gemm_mfma_kernel<<<dim3(256, 4, 2), 256, 0, stream>>>(
      m, w2f, w2b, bs + 1024, bs + 1536, pref, preb, 256);
  lstm_kernel<<<dim3(64, 2), 1024, 0, stream>>>(pref, preb, l2f_Whh, l2b_Whh, m2);

  logits_kernel<<<8192, 256, 0, stream>>>(m2, W1, b1, gz1, z);
  softmax_t_kernel<<<64, 512, 0, stream>>>(z, p2);
}

// Round 13
// 962.959 us; speedup vs baseline: 1.6154x; 1.6154x over previous
//
#include <hip/hip_runtime.h>
#include <hip/hip_bf16.h>
#include <cstdint>
#include <cstddef>

// Shapes: B=64, T=512, J=64, D=256, E=128, gdim=8E=1024, gates=4E=512
// ws layout (bytes), total 137,371,648 (~131 MiB):
//   [0,           67,108,864)  g bf16 (32768 x 1024)  SWIZZLED (see below)
//        aliased: m  bf16 (32768 x 256) at 0 ; m2 bf16 at 33,554,432 (unswizzled)
//   [67,108,864, 100,663,296)  pre_f bf16 (32768 x 512)  [cell][gate] layout
//   [100,663,296,134,217,728)  pre_b bf16 (32768 x 512)  [cell][gate] layout
//   [134,217,728,134,742,016)  gz0, gz1, smax, z (32768 fp32 each)
//   [134,742,016,135,790,592)  w1f bf16 (512x1024) SWIZZLED
//   [135,790,592,136,839,168)  w1b bf16            SWIZZLED
//   [136,839,168,137,101,312)  w2f bf16 (512x256)  linear
//   [137,101,312,137,363,456)  w2b bf16            linear
//   [137,363,456,137,371,648)  bs[4][512] fp32 (bih+bhh, l1f/l1b/l2f/l2b)
//
// SWIZZLE (g, w1f, w1b; rule #21 both-sides): rows of 1024 bf16 = 128 chunks
// of 8 bf16 (16B). Element (row, col): stored chunk = (col>>3) with LOW 3 BITS
// XOR'd by (row&7). gemm1 stages linearly via global_load_lds (LDS [128][64],
// no pad) and applies the same XOR on the ds_read address -> conflict-free.

typedef short short8v __attribute__((ext_vector_type(8)));
typedef float f32x4 __attribute__((ext_vector_type(4)));
typedef unsigned short ushort8v __attribute__((ext_vector_type(8)));
typedef unsigned short ushort4v __attribute__((ext_vector_type(4)));

static __device__ __forceinline__ float bf2f(unsigned short u) {
  return __uint_as_float(((unsigned int)u) << 16);
}
static __device__ __forceinline__ unsigned short f2bf(float f) {  // RNE
  unsigned int u = __float_as_uint(f);
  return (unsigned short)((u + 0x7FFFu + ((u >> 16) & 1u)) >> 16);
}
static __device__ __forceinline__ float fsig(float x) {
  return 1.f / (1.f + __expf(-x));
}
static __device__ __forceinline__ float ftanh(float x) {
  return 1.f - 2.f / (__expf(2.f * x) + 1.f);
}
// swizzled column (in shorts) for logical (row, col) in a 1024-wide row
static __device__ __forceinline__ int swzcol(int row, int col) {
  int ch = col >> 3;
  int cs = (ch & ~7) | ((ch ^ row) & 7);
  return cs * 8 + (col & 7);
}
static __device__ __forceinline__ void gld_lds16(const void* g, void* l) {
  __builtin_amdgcn_global_load_lds(
      (const __attribute__((address_space(1))) unsigned int*)g,
      (__attribute__((address_space(3))) unsigned int*)l, 16, 0, 0);
}

// ---------------- weight pre-convert: 4x Wih fp32->bf16, bias sums ----------
// w1f/w1b written SWIZZLED; w2f/w2b linear.
__global__ __launch_bounds__(256) void cvt_w_kernel(
    const float* __restrict__ w1f, const float* __restrict__ w1b,
    const float* __restrict__ w2f, const float* __restrict__ w2b,
    const float* __restrict__ b1fi, const float* __restrict__ b1fh,
    const float* __restrict__ b1bi, const float* __restrict__ b1bh,
    const float* __restrict__ b2fi, const float* __restrict__ b2fh,
    const float* __restrict__ b2bi, const float* __restrict__ b2bh,
    unsigned short* __restrict__ d1f, unsigned short* __restrict__ d1b,
    unsigned short* __restrict__ d2f, unsigned short* __restrict__ d2b,
    float* __restrict__ bs)
{
  const int bid = blockIdx.x, tid = threadIdx.x;
  if (bid < 1280) {
    int idx = (bid * 256 + tid) * 4;
    const float* src;
    unsigned short* dst;
    int off;
    bool swz;
    if (idx < 524288)        { src = w1f; dst = d1f; off = idx; swz = true; }
    else if (idx < 1048576)  { src = w1b; dst = d1b; off = idx - 524288; swz = true; }
    else if (idx < 1179648)  { src = w2f; dst = d2f; off = idx - 1048576; swz = false; }
    else                     { src = w2b; dst = d2b; off = idx - 1179648; swz = false; }
    float4 f = *(const float4*)(src + off);
    ushort4v v;
    v[0] = f2bf(f.x); v[1] = f2bf(f.y); v[2] = f2bf(f.z); v[3] = f2bf(f.w);
    if (swz) {
      int row = off >> 10, col = off & 1023;
      *(ushort4v*)(dst + ((size_t)row << 10) + swzcol(row, col)) = v;
    } else {
      *(ushort4v*)(dst + off) = v;
    }
  } else {
    int bidx = (bid - 1280) * 256 + tid;   // 0..2047
    int which = bidx >> 9, col = bidx & 511;
    float v;
    if (which == 0)      v = b1fi[col] + b1fh[col];
    else if (which == 1) v = b1bi[col] + b1bh[col];
    else if (which == 2) v = b2fi[col] + b2fh[col];
    else                 v = b2bi[col] + b2bh[col];
    bs[bidx] = v;
  }
}

// ---------------- MFMA attention (r11 winner; g writes now swizzled) --------
__global__ __launch_bounds__(256) void attn_kernel(
    const float* __restrict__ c, const float* __restrict__ q,
    const float* __restrict__ wc, const float* __restrict__ bc,
    const float* __restrict__ wq, const float* __restrict__ bq,
    const float* __restrict__ wcq, const float* __restrict__ bcq,
    const float* __restrict__ W0, const float* __restrict__ W1,
    __hip_bfloat16* __restrict__ g, float* __restrict__ smax,
    float* __restrict__ gz0, float* __restrict__ gz1)
{
  __shared__ unsigned short cbf[128][264];  // c bf16 (A for S; cv in epilogue)
  __shared__ unsigned short qhb[64][264];   // qhat bf16 j-major (B for S)
  __shared__ unsigned short qtb[256][72];   // q bf16 d-major (B for c2q)
  __shared__ unsigned short Pbuf[4][16][72];// per-wave P transpose (A for c2q)
  __shared__ float qwqs[64];
  __shared__ float qwp[4][64];
  const int b = blockIdx.x, tid = threadIdx.x;
  const int wave = tid >> 6, lane = tid & 63;
  const int t0 = blockIdx.y * 128;
  unsigned short* gbase = (unsigned short*)g;

  #pragma unroll
  for (int i = 0; i < 16; ++i) {
    int idx = tid + i * 256;               // 4096 float4
    int j = idx >> 6, d4 = (idx & 63) * 4;
    float4 v = *(const float4*)&q[((size_t)b * 64 + j) * 256 + d4];
    float4 w4 = *(const float4*)&wcq[d4];
    float4 c4 = *(const float4*)&wc[d4];
    qhb[j][d4 + 0] = f2bf(v.x * w4.x + c4.x);
    qhb[j][d4 + 1] = f2bf(v.y * w4.y + c4.y);
    qhb[j][d4 + 2] = f2bf(v.z * w4.z + c4.z);
    qhb[j][d4 + 3] = f2bf(v.w * w4.w + c4.w);
    qtb[d4 + 0][j] = f2bf(v.x);
    qtb[d4 + 1][j] = f2bf(v.y);
    qtb[d4 + 2][j] = f2bf(v.z);
    qtb[d4 + 3][j] = f2bf(v.w);
  }
  #pragma unroll
  for (int i = 0; i < 32; ++i) {
    int idx = tid + i * 256;               // 8192 float4
    int r = idx >> 6, d4 = (idx & 63) * 4;
    float4 v = *(const float4*)&c[((size_t)b * 512 + t0 + r) * 256 + d4];
    ushort4v u;
    u[0] = f2bf(v.x); u[1] = f2bf(v.y); u[2] = f2bf(v.z); u[3] = f2bf(v.w);
    *(ushort4v*)&cbf[r][d4] = u;
    // swizzled g write (row&7 == r&7 since b*512 and t0 are 8-aligned)
    *(ushort4v*)&gbase[((size_t)b * 512 + t0 + r) * 1024 + swzcol(r, d4)] = u;
  }
  __syncthreads();
  {
    float s = 0.f;
    for (int dd = 0; dd < 64; ++dd) {
      int d = wave * 64 + dd;
      s += bf2f(qtb[d][lane]) * wq[d];
    }
    qwp[wave][lane] = s;
  }
  __syncthreads();
  if (tid < 64) qwqs[tid] = qwp[0][tid] + qwp[1][tid] + qwp[2][tid] + qwp[3][tid] + bq[0];
  __syncthreads();

  const int cl = lane & 15, kg = lane >> 4;
  const float sbias = bc[0] + bcq[0];

  #pragma unroll
  for (int half = 0; half < 2; ++half) {
    const int tt = wave + half * 4;
    const int rowb = tt * 16;
    f32x4 acc[4] = {};
    #pragma unroll
    for (int kt = 0; kt < 8; ++kt) {
      short8v a = *(const short8v*)&cbf[rowb + cl][kt * 32 + kg * 8];
      #pragma unroll
      for (int jt = 0; jt < 4; ++jt) {
        short8v bq_ = *(const short8v*)&qhb[jt * 16 + cl][kt * 32 + kg * 8];
        acc[jt] = __builtin_amdgcn_mfma_f32_16x16x32_bf16(a, bq_, acc[jt], 0, 0, 0);
      }
    }
    #pragma unroll
    for (int jt = 0; jt < 4; ++jt) {
      float qadd = qwqs[jt * 16 + cl] + sbias;
      #pragma unroll
      for (int r = 0; r < 4; ++r) acc[jt][r] += qadd;
    }
    f32x4 mx = acc[0];
    #pragma unroll
    for (int jt = 1; jt < 4; ++jt)
      #pragma unroll
      for (int r = 0; r < 4; ++r) mx[r] = fmaxf(mx[r], acc[jt][r]);
    #pragma unroll
    for (int off = 1; off < 16; off <<= 1)
      #pragma unroll
      for (int r = 0; r < 4; ++r) mx[r] = fmaxf(mx[r], __shfl_xor(mx[r], off));
    f32x4 se = {0.f, 0.f, 0.f, 0.f};
    #pragma unroll
    for (int jt = 0; jt < 4; ++jt)
      #pragma unroll
      for (int r = 0; r < 4; ++r) {
        acc[jt][r] = __expf(acc[jt][r] - mx[r]);
        se[r] += acc[jt][r];
      }
    #pragma unroll
    for (int off = 1; off < 16; off <<= 1)
      #pragma unroll
      for (int r = 0; r < 4; ++r) se[r] += __shfl_xor(se[r], off);
    f32x4 inv;
    #pragma unroll
    for (int r = 0; r < 4; ++r) inv[r] = 1.f / se[r];
    #pragma unroll
    for (int jt = 0; jt < 4; ++jt)
      #pragma unroll
      for (int r = 0; r < 4; ++r)
        Pbuf[wave][4 * kg + r][jt * 16 + cl] = f2bf(acc[jt][r] * inv[r]);
    if (cl == 0) {
      #pragma unroll
      for (int r = 0; r < 4; ++r)
        smax[(size_t)b * 512 + t0 + rowb + 4 * kg + r] = mx[r];
    }
    f32x4 gz0p = {0.f, 0.f, 0.f, 0.f}, gz1p = {0.f, 0.f, 0.f, 0.f};
    for (int dt = 0; dt < 16; ++dt) {
      f32x4 ca = {0.f, 0.f, 0.f, 0.f};
      #pragma unroll
      for (int kt = 0; kt < 2; ++kt) {
        short8v pa = *(const short8v*)&Pbuf[wave][cl][kt * 32 + kg * 8];
        short8v qb_ = *(const short8v*)&qtb[dt * 16 + cl][kt * 32 + kg * 8];
        ca = __builtin_amdgcn_mfma_f32_16x16x32_bf16(pa, qb_, ca, 0, 0, 0);
      }
      int d = dt * 16 + cl;
      float w0a = W0[d], w0b_ = W0[256 + d], w0c2 = W0[512 + d];
      float w1a = W1[d], w1b2 = W1[256 + d], w1c2 = W1[512 + d];
      #pragma unroll
      for (int r = 0; r < 4; ++r) {
        int rloc = rowb + 4 * kg + r;
        float cv = bf2f(cbf[rloc][d]);
        float av = ca[r];
        float pr = cv * av;
        size_t gr = ((size_t)b * 512 + t0 + rloc) * 1024;
        gbase[gr + swzcol(rloc, 256 + d)] = f2bf(av);
        gbase[gr + swzcol(rloc, 512 + d)] = f2bf(pr);
        gz0p[r] += cv * w0a + av * w0b_ + pr * w0c2;
        gz1p[r] += cv * w1a + av * w1b2 + pr * w1c2;
      }
    }
    #pragma unroll
    for (int off = 1; off < 16; off <<= 1)
      #pragma unroll
      for (int r = 0; r < 4; ++r) {
        gz0p[r] += __shfl_xor(gz0p[r], off);
        gz1p[r] += __shfl_xor(gz1p[r], off);
      }
    if (cl == 0) {
      #pragma unroll
      for (int r = 0; r < 4; ++r) {
        size_t rw = (size_t)b * 512 + t0 + rowb + 4 * kg + r;
        gz0[rw] = gz0p[r];
        gz1[rw] = gz1p[r];
      }
    }
  }
}

// ---------------- b_att softmax over t, q2c, g[768:1024] (swizzled), gz tail ----
__global__ __launch_bounds__(256) void batt_kernel(
    const float* __restrict__ c, const float* __restrict__ smax,
    const float* __restrict__ W0, const float* __restrict__ W1,
    __hip_bfloat16* __restrict__ g,
    float* __restrict__ gz0, float* __restrict__ gz1)
{
  __shared__ float sm[512];
  __shared__ float red[4], red2[4];
  __shared__ float q2c_s[256];
  const int b = blockIdx.x, tid = threadIdx.x;
  float v0 = smax[(size_t)b * 512 + tid];
  float v1 = smax[(size_t)b * 512 + tid + 256];
  float m = fmaxf(v0, v1);
  #pragma unroll
  for (int off = 32; off; off >>= 1) m = fmaxf(m, __shfl_xor(m, off));
  if ((tid & 63) == 0) red[tid >> 6] = m;
  __syncthreads();
  float M = fmaxf(fmaxf(red[0], red[1]), fmaxf(red[2], red[3]));
  float e0 = expf(v0 - M), e1 = expf(v1 - M);
  float ssum = e0 + e1;
  #pragma unroll
  for (int off = 32; off; off >>= 1) ssum += __shfl_xor(ssum, off);
  if ((tid & 63) == 0) red2[tid >> 6] = ssum;
  __syncthreads();
  float S = red2[0] + red2[1] + red2[2] + red2[3];
  sm[tid] = e0 / S;
  sm[tid + 256] = e1 / S;
  __syncthreads();
  float acc = 0.f;
  #pragma unroll 8
  for (int t = 0; t < 512; ++t) acc += sm[t] * c[((size_t)b * 512 + t) * 256 + tid];
  q2c_s[tid] = acc;
  __syncthreads();
  const int wave = tid >> 6, lane = tid & 63;
  float qv[4], w0c[4], w1c[4];
  #pragma unroll
  for (int r = 0; r < 4; ++r) {
    int d = lane + 64 * r;
    qv[r]  = q2c_s[d];
    w0c[r] = W0[768 + d];
    w1c[r] = W1[768 + d];
  }
  for (int t = wave; t < 512; t += 4) {
    size_t row = (size_t)b * 512 + t;
    float s0 = 0.f, s1 = 0.f;
    #pragma unroll
    for (int r = 0; r < 4; ++r) {
      int d = lane + 64 * r;
      float v = c[row * 256 + d];
      float gv = v * qv[r];
      g[row * 1024 + swzcol(t, 768 + d)] = __float2bfloat16(gv);
      s0 += gv * w0c[r];
      s1 += gv * w1c[r];
    }
    #pragma unroll
    for (int off = 32; off; off >>= 1) {
      s0 += __shfl_xor(s0, off);
      s1 += __shfl_xor(s1, off);
    }
    if (lane == 0) { gz0[row] += s0; gz1[row] += s1; }
  }
}

// ---------------- gemm1: pre = g_swz @ W_swz^T + bs, via global_load_lds -------
// grid (256, 4, 2), block 256 (4 waves, each 64x64). K=1024. LDS linear [128][64]
// (no pad); reads apply the chunk-XOR swizzle -> 2-way banks (free).
__global__ __launch_bounds__(256) void gemm1_kernel(
    const unsigned short* __restrict__ X,
    const unsigned short* __restrict__ Wf, const unsigned short* __restrict__ Wb,
    const float* __restrict__ bsf, const float* __restrict__ bsb,
    __hip_bfloat16* __restrict__ Yf, __hip_bfloat16* __restrict__ Yb)
{
  __shared__ unsigned short Xs[128 * 64];
  __shared__ unsigned short Ws[128 * 64];
  const unsigned short* W = blockIdx.z ? Wb : Wf;
  const float* bs = blockIdx.z ? bsb : bsf;
  __hip_bfloat16* Y = blockIdx.z ? Yb : Yf;
  const int tid = threadIdx.x;
  const int m0 = blockIdx.x * 128, n0 = blockIdx.y * 128;
  const int lane = tid & 63, wave = tid >> 6;
  const int wr = wave >> 1, wc = wave & 1;
  const int frow = lane & 15, kg = lane >> 4;
  const int r7 = frow & 7;
  // per-lane global chunk decode for staging
  const int cid_l = wave * 64 + lane;        // chunk id base (i adds 256)

  f32x4 acc[4][4] = {};
  for (int kt = 0; kt < 1024; kt += 64) {
    #pragma unroll
    for (int i = 0; i < 4; ++i) {
      int cb = i * 256 + wave * 64;          // wave-uniform chunk base
      int cid = i * 256 + cid_l;
      int row = cid >> 3, ch = cid & 7;
      gld_lds16(X + (size_t)(m0 + row) * 1024 + kt + ch * 8, Xs + cb * 8);
      gld_lds16(W + (size_t)(n0 + row) * 1024 + kt + ch * 8, Ws + cb * 8);
    }
    __syncthreads();
    #pragma unroll
    for (int kk = 0; kk < 64; kk += 32) {
      const int pc = (((kk >> 3) + kg) ^ r7) * 8;   // physical chunk offset (shorts)
      short8v a[4], bfr[4];
      #pragma unroll
      for (int i = 0; i < 4; ++i)
        a[i] = *(const short8v*)&Xs[(wr * 64 + i * 16 + frow) * 64 + pc];
      #pragma unroll
      for (int j = 0; j < 4; ++j)
        bfr[j] = *(const short8v*)&Ws[(wc * 64 + j * 16 + frow) * 64 + pc];
      #pragma unroll
      for (int i = 0; i < 4; ++i)
        #pragma unroll
        for (int j = 0; j < 4; ++j)
          acc[i][j] = __builtin_amdgcn_mfma_f32_16x16x32_bf16(a[i], bfr[j], acc[i][j], 0, 0, 0);
    }
    __syncthreads();
  }
  const int r0 = kg * 4;
  #pragma unroll
  for (int j = 0; j < 4; ++j) {
    int col = n0 + wc * 64 + j * 16 + frow;
    int colp = (col & 127) * 4 + (col >> 7);   // [cell][gate] permuted layout
    float bsum = bs[col];
    #pragma unroll
    for (int i = 0; i < 4; ++i) {
      int rowb = m0 + wr * 64 + i * 16 + r0;
      #pragma unroll
      for (int r = 0; r < 4; ++r)
        Y[(size_t)(rowb + r) * 512 + colp] = __float2bfloat16(acc[i][j][r] + bsum);
    }
  }
}

// ---------------- MFMA GEMM (layer 2, linear W/m, reg-staged; unchanged) ------
__global__ __launch_bounds__(256) void gemm_mfma_kernel(
    const __hip_bfloat16* __restrict__ Xg,
    const unsigned short* __restrict__ Wf, const unsigned short* __restrict__ Wb,
    const float* __restrict__ bsf, const float* __restrict__ bsb,
    __hip_bfloat16* __restrict__ Yf, __hip_bfloat16* __restrict__ Yb, int K)
{
  __shared__ unsigned short Xs[128 * 72];
  __shared__ unsigned short Ws[128 * 72];
  const unsigned short* X = (const unsigned short*)Xg;
  const unsigned short* W = blockIdx.z ? Wb : Wf;
  const float* bs = blockIdx.z ? bsb : bsf;
  __hip_bfloat16* Y = blockIdx.z ? Yb : Yf;
  const int tid = threadIdx.x;
  const int m0 = blockIdx.x * 128, n0 = blockIdx.y * 128;
  const int lane = tid & 63, wave = tid >> 6;
  const int wr = wave >> 1, wc = wave & 1;
  const int frow = lane & 15, fk = (lane >> 4) * 8;

  f32x4 acc[4][4] = {};
  for (int kt = 0; kt < K; kt += 64) {
    #pragma unroll
    for (int i = 0; i < 4; ++i) {
      int cidx = tid + 256 * i;          // 0..1023
      int row = cidx >> 3, kc = cidx & 7;
      *(ushort8v*)&Xs[row * 72 + kc * 8] =
          *(const ushort8v*)&X[(size_t)(m0 + row) * K + kt + kc * 8];
      *(ushort8v*)&Ws[row * 72 + kc * 8] =
          *(const ushort8v*)&W[(size_t)(n0 + row) * K + kt + kc * 8];
    }
    __syncthreads();
    #pragma unroll
    for (int kk = 0; kk < 64; kk += 32) {
      short8v a[4], bfr[4];
      #pragma unroll
      for (int i = 0; i < 4; ++i)
        a[i] = *(const short8v*)&Xs[(wr * 64 + i * 16 + frow) * 72 + kk + fk];
      #pragma unroll
      for (int j = 0; j < 4; ++j)
        bfr[j] = *(const short8v*)&Ws[(wc * 64 + j * 16 + frow) * 72 + kk + fk];
      #pragma unroll
      for (int i = 0; i < 4; ++i)
        #pragma unroll
        for (int j = 0; j < 4; ++j)
          acc[i][j] = __builtin_amdgcn_mfma_f32_16x16x32_bf16(a[i], bfr[j], acc[i][j], 0, 0, 0);
    }
    __syncthreads();
  }
  const int r0 = (lane >> 4) * 4;
  #pragma unroll
  for (int j = 0; j < 4; ++j) {
    int col = n0 + wc * 64 + j * 16 + (lane & 15);
    int colp = (col & 127) * 4 + (col >> 7);
    float bsum = bs[col];
    #pragma unroll
    for (int i = 0; i < 4; ++i) {
      int rowb = m0 + wr * 64 + i * 16 + r0;
      #pragma unroll
      for (int r = 0; r < 4; ++r)
        Y[(size_t)(rowb + r) * 512 + colp] = __float2bfloat16(acc[i][j][r] + bsum);
    }
  }
}

// ---------------- LSTM recurrence via MFMA, 8-step chunked I/O (r10 winner) ---
// grid (64, 2) block 512 (8 waves). 512 threads is the measured sweet spot:
// r12's 16-wave variant doubled step time (barrier skew scales w/ waves/block).
__global__ __launch_bounds__(512, 2) void lstm_kernel(
    const __hip_bfloat16* __restrict__ pre_f, const __hip_bfloat16* __restrict__ pre_b,
    const float* __restrict__ Whh_f, const float* __restrict__ Whh_b,
    __hip_bfloat16* __restrict__ out)
{
  const int b = blockIdx.x, dir = blockIdx.y;
  const unsigned short* __restrict__ pre =
      (const unsigned short*)(dir ? pre_b : pre_f);
  const float* __restrict__ Whh = dir ? Whh_b : Whh_f;
  const int off = dir ? 128 : 0;
  const int tid = threadIdx.x;
  const int wave = tid >> 6, lane = tid & 63;
  const int cl = lane & 15;            // col / cell-within-wave
  const int kg = lane >> 4;            // k-group 0..3
  const int cell = wave * 16 + cl;     // 0..127

#define LOAD_BF(Q, T, DST)                                            \
  {                                                                   \
    const float* wp = Whh + (size_t)(Q * 128 + cell) * 128 + T * 32 + kg * 8; \
    float4 f0 = *(const float4*)wp;                                   \
    float4 f1 = *(const float4*)(wp + 4);                             \
    DST[0] = (short)f2bf(f0.x); DST[1] = (short)f2bf(f0.y);           \
    DST[2] = (short)f2bf(f0.z); DST[3] = (short)f2bf(f0.w);           \
    DST[4] = (short)f2bf(f1.x); DST[5] = (short)f2bf(f1.y);           \
    DST[6] = (short)f2bf(f1.z); DST[7] = (short)f2bf(f1.w);           \
    asm volatile("" : "+v"(DST));                                     \
  }
  short8v bf00, bf01, bf02, bf03, bf10, bf11, bf12, bf13;
  short8v bf20, bf21, bf22, bf23, bf30, bf31, bf32, bf33;
  LOAD_BF(0, 0, bf00) LOAD_BF(0, 1, bf01) LOAD_BF(0, 2, bf02) LOAD_BF(0, 3, bf03)
  LOAD_BF(1, 0, bf10) LOAD_BF(1, 1, bf11) LOAD_BF(1, 2, bf12) LOAD_BF(1, 3, bf13)
  LOAD_BF(2, 0, bf20) LOAD_BF(2, 1, bf21) LOAD_BF(2, 2, bf22) LOAD_BF(2, 3, bf23)
  LOAD_BF(3, 0, bf30) LOAD_BF(3, 1, bf31) LOAD_BF(3, 2, bf32) LOAD_BF(3, 3, bf33)
#undef LOAD_BF

  __shared__ unsigned short hbuf[2][128];
  if (tid < 128) { hbuf[0][tid] = 0; hbuf[1][tid] = 0; }
  __syncthreads();

  const size_t base = (size_t)b * 512;
  const int tstep = dir ? -1 : 1;
  const int t0 = dir ? 511 : 0;
  const unsigned short* prow = pre + base * 512 + cell * 4;
  unsigned short* orow = (unsigned short*)out + base * 256 + off + cell;

  int cur = 0;
  float cst = 0.f;
  f32x4 acc0 = {0.f, 0.f, 0.f, 0.f};
  f32x4 acc1 = acc0, acc2 = acc0, acc3 = acc0;

#define LSTM_STEP(P, HOUT)                                                  \
  {                                                                         \
    const unsigned short* hb = hbuf[cur];                                   \
    short8v a0 = *(const short8v*)(hb +  0 + kg * 8);                       \
    short8v a1 = *(const short8v*)(hb + 32 + kg * 8);                       \
    short8v a2 = *(const short8v*)(hb + 64 + kg * 8);                       \
    short8v a3 = *(const short8v*)(hb + 96 + kg * 8);                       \
    acc0[0] = bf2f(P[0]); acc1[0] = bf2f(P[1]);                             \
    acc2[0] = bf2f(P[2]); acc3[0] = bf2f(P[3]);                             \
    acc0 = __builtin_amdgcn_mfma_f32_16x16x32_bf16(a0, bf00, acc0, 0, 0, 0);\
    acc1 = __builtin_amdgcn_mfma_f32_16x16x32_bf16(a0, bf10, acc1, 0, 0, 0);\
    acc2 = __builtin_amdgcn_mfma_f32_16x16x32_bf16(a0, bf20, acc2, 0, 0, 0);\
    acc3 = __builtin_amdgcn_mfma_f32_16x16x32_bf16(a0, bf30, acc3, 0, 0, 0);\
    acc0 = __builtin_amdgcn_mfma_f32_16x16x32_bf16(a1, bf01, acc0, 0, 0, 0);\
    acc1 = __builtin_amdgcn_mfma_f32_16x16x32_bf16(a1, bf11, acc1, 0, 0, 0);\
    acc2 = __builtin_amdgcn_mfma_f32_16x16x32_bf16(a1, bf21, acc2, 0, 0, 0);\
    acc3 = __builtin_amdgcn_mfma_f32_16x16x32_bf16(a1, bf31, acc3, 0, 0, 0);\
    acc0 = __builtin_amdgcn_mfma_f32_16x16x32_bf16(a2, bf02, acc0, 0, 0, 0);\
    acc1 = __builtin_amdgcn_mfma_f32_16x16x32_bf16(a2, bf12, acc1, 0, 0, 0);\
    acc2 = __builtin_amdgcn_mfma_f32_16x16x32_bf16(a2, bf22, acc2, 0, 0, 0);\
    acc3 = __builtin_amdgcn_mfma_f32_16x16x32_bf16(a2, bf32, acc3, 0, 0, 0);\
    acc0 = __builtin_amdgcn_mfma_f32_16x16x32_bf16(a3, bf03, acc0, 0, 0, 0);\
    acc1 = __builtin_amdgcn_mfma_f32_16x16x32_bf16(a3, bf13, acc1, 0, 0, 0);\
    acc2 = __builtin_amdgcn_mfma_f32_16x16x32_bf16(a3, bf23, acc2, 0, 0, 0);\
    acc3 = __builtin_amdgcn_mfma_f32_16x16x32_bf16(a3, bf33, acc3, 0, 0, 0);\
    float gi_ = fsig(acc0[0]);                                              \
    float gf_ = fsig(acc1[0]);                                              \
    float gg_ = ftanh(acc2[0]);                                             \
    float go_ = fsig(acc3[0]);                                              \
    cst = gf_ * cst + gi_ * gg_;                                            \
    float hv = go_ * ftanh(cst);                                            \
    HOUT = f2bf(hv);                                                        \
    if (lane < 16) hbuf[cur ^ 1][cell] = HOUT;                              \
    __syncthreads();                                                        \
    cur ^= 1;                                                               \
  }

  for (int chunk = 0; chunk < 64; ++chunk) {
    const int tb = t0 + chunk * 8 * tstep;
    ushort4v p0 = *(const ushort4v*)(prow + (size_t)(tb)             * 512);
    ushort4v p1 = *(const ushort4v*)(prow + (size_t)(tb + 1 * tstep) * 512);
    ushort4v p2 = *(const ushort4v*)(prow + (size_t)(tb + 2 * tstep) * 512);
    ushort4v p3 = *(const ushort4v*)(prow + (size_t)(tb + 3 * tstep) * 512);
    ushort4v p4 = *(const ushort4v*)(prow + (size_t)(tb + 4 * tstep) * 512);
    ushort4v p5 = *(const ushort4v*)(prow + (size_t)(tb + 5 * tstep) * 512);
    ushort4v p6 = *(const ushort4v*)(prow + (size_t)(tb + 6 * tstep) * 512);
    ushort4v p7 = *(const ushort4v*)(prow + (size_t)(tb + 7 * tstep) * 512);
    unsigned short h0, h1, h2, h3, h4, h5, h6, h7;
    LSTM_STEP(p0, h0)
    LSTM_STEP(p1, h1)
    LSTM_STEP(p2, h2)
    LSTM_STEP(p3, h3)
    LSTM_STEP(p4, h4)
    LSTM_STEP(p5, h5)
    LSTM_STEP(p6, h6)
    LSTM_STEP(p7, h7)
    if (lane < 16) {
      orow[(size_t)(tb)             * 256] = h0;
      orow[(size_t)(tb + 1 * tstep) * 256] = h1;
      orow[(size_t)(tb + 2 * tstep) * 256] = h2;
      orow[(size_t)(tb + 3 * tstep) * 256] = h3;
      orow[(size_t)(tb + 4 * tstep) * 256] = h4;
      orow[(size_t)(tb + 5 * tstep) * 256] = h5;
      orow[(size_t)(tb + 6 * tstep) * 256] = h6;
      orow[(size_t)(tb + 7 * tstep) * 256] = h7;
    }
  }
#undef LSTM_STEP
}

// ---------------- logits: z[row] = gz[row] + m_row(bf16) . W[1024:1280] + bias ----
__global__ __launch_bounds__(256) void logits_kernel(
    const __hip_bfloat16* __restrict__ m, const float* __restrict__ W,
    const float* __restrict__ bias, const float* __restrict__ gz,
    float* __restrict__ z)
{
  const int row = blockIdx.x * 4 + (threadIdx.x >> 6);
  const int lane = threadIdx.x & 63;
  const unsigned short* mrow = (const unsigned short*)m + (size_t)row * 256;
  float acc = 0.f;
  #pragma unroll
  for (int i = 0; i < 4; ++i) acc += bf2f(mrow[lane + 64 * i]) * W[1024 + lane + 64 * i];
  #pragma unroll
  for (int off = 32; off; off >>= 1) acc += __shfl_xor(acc, off);
  if (lane == 0) z[row] = acc + gz[row] + bias[0];
}

// ---------------- softmax over t ----------------
__global__ __launch_bounds__(512) void softmax_t_kernel(
    const float* __restrict__ z, float* __restrict__ p)
{
  const int b = blockIdx.x, t = threadIdx.x;
  __shared__ float red[8], red2[8];
  float v = z[(size_t)b * 512 + t];
  float m = v;
  #pragma unroll
  for (int off = 32; off; off >>= 1) m = fmaxf(m, __shfl_xor(m, off));
  if ((t & 63) == 0) red[t >> 6] = m;
  __syncthreads();
  float M = red[0];
  #pragma unroll
  for (int i = 1; i < 8; ++i) M = fmaxf(M, red[i]);
  float e = expf(v - M);
  float s = e;
  #pragma unroll
  for (int off = 32; off; off >>= 1) s += __shfl_xor(s, off);
  if ((t & 63) == 0) red2[t >> 6] = s;
  __syncthreads();
  float S = red2[0];
  #pragma unroll
  for (int i = 1; i < 8; ++i) S += red2[i];
  p[(size_t)b * 512 + t] = e / S;
}

extern "C" void kernel_launch(void* const* d_in, const int* in_sizes, int n_in,
                              void* d_out, int out_size, void* d_ws, size_t ws_size,
                              hipStream_t stream)
{
  const float* c   = (const float*)d_in[0];
  const float* q   = (const float*)d_in[1];
  const float* wc  = (const float*)d_in[2];
  const float* bc  = (const float*)d_in[3];
  const float* wq  = (const float*)d_in[4];
  const float* bq  = (const float*)d_in[5];
  const float* wcq = (const float*)d_in[6];
  const float* bcq = (const float*)d_in[7];
  const float* l1f_Wih = (const float*)d_in[8];
  const float* l1f_Whh = (const float*)d_in[9];
  const float* l1f_bih = (const float*)d_in[10];
  const float* l1f_bhh = (const float*)d_in[11];
  const float* l1b_Wih = (const float*)d_in[12];
  const float* l1b_Whh = (const float*)d_in[13];
  const float* l1b_bih = (const float*)d_in[14];
  const float* l1b_bhh = (const float*)d_in[15];
  const float* l2f_Wih = (const float*)d_in[16];
  const float* l2f_Whh = (const float*)d_in[17];
  const float* l2f_bih = (const float*)d_in[18];
  const float* l2f_bhh = (const float*)d_in[19];
  const float* l2b_Wih = (const float*)d_in[20];
  const float* l2b_Whh = (const float*)d_in[21];
  const float* l2b_bih = (const float*)d_in[22];
  const float* l2b_bhh = (const float*)d_in[23];
  const float* W0 = (const float*)d_in[24];
  const float* b0 = (const float*)d_in[25];
  const float* W1 = (const float*)d_in[26];
  const float* b1 = (const float*)d_in[27];

  const size_t required = 137371648u;
  if (ws_size < required) return;

  char* wsb = (char*)d_ws;
  __hip_bfloat16* gbf = (__hip_bfloat16*)wsb;
  __hip_bfloat16* m   = (__hip_bfloat16*)wsb;
  __hip_bfloat16* m2  = (__hip_bfloat16*)(wsb + 33554432);
  __hip_bfloat16* pref = (__hip_bfloat16*)(wsb + 67108864);
  __hip_bfloat16* preb = (__hip_bfloat16*)(wsb + 100663296);
  float* gz0  = (float*)(wsb + 134217728);
  float* gz1  = gz0 + 32768;
  float* smax = gz1 + 32768;
  float* z    = smax + 32768;
  unsigned short* w1f = (unsigned short*)(wsb + 134742016);
  unsigned short* w1b = (unsigned short*)(wsb + 135790592);
  unsigned short* w2f = (unsigned short*)(wsb + 136839168);
  unsigned short* w2b = (unsigned short*)(wsb + 137101312);
  float* bs = (float*)(wsb + 137363456);
  float* p1 = (float*)d_out;
  float* p2 = p1 + 32768;

  cvt_w_kernel<<<1288, 256, 0, stream>>>(l1f_Wih, l1b_Wih, l2f_Wih, l2b_Wih,
                                         l1f_bih, l1f_bhh, l1b_bih, l1b_bhh,
                                         l2f_bih, l2f_bhh, l2b_bih, l2b_bhh,
                                         w1f, w1b, w2f, w2b, bs);
  attn_kernel<<<dim3(64, 4), 256, 0, stream>>>(c, q, wc, bc, wq, bq, wcq, bcq,
                                               W0, W1, gbf, smax, gz0, gz1);
  batt_kernel<<<64, 256, 0, stream>>>(c, smax, W0, W1, gbf, gz0, gz1);

  gemm1_kernel<<<dim3(256, 4, 2), 256, 0, stream>>>(
      (const unsigned short*)gbf, w1f, w1b, bs, bs + 512, pref, preb);
  lstm_kernel<<<dim3(64, 2), 512, 0, stream>>>(pref, preb, l1f_Whh, l1b_Whh, m);

  logits_kernel<<<8192, 256, 0, stream>>>(m, W0, b0, gz0, z);
  softmax_t_kernel<<<64, 512, 0, stream>>>(z, p1);

  gemm_mfma_kernel<<<dim3(256, 4, 2), 256, 0, stream>>>(
      m, w2f, w2b, bs + 1024, bs + 1536, pref, preb, 256);
  lstm_kernel<<<dim3(64, 2), 512, 0, stream>>>(pref, preb, l2f_Whh, l2b_Whh, m2);

  logits_kernel<<<8192, 256, 0, stream>>>(m2, W1, b1, gz1, z);
  softmax_t_kernel<<<64, 512, 0, stream>>>(z, p2);
}

// Round 14
// 957.033 us; speedup vs baseline: 1.6254x; 1.0062x over previous
//
#include <hip/hip_runtime.h>
#include <hip/hip_bf16.h>
#include <cstdint>
#include <cstddef>

// Shapes: B=64, T=512, J=64, D=256, E=128, gdim=8E=1024, gates=4E=512
// ws layout (bytes), total 137,371,648 (~131 MiB):
//   [0,           67,108,864)  g bf16 (32768 x 1024)  SWIZZLED (see below)
//        aliased: m  bf16 (32768 x 256) at 0 ; m2 bf16 at 33,554,432 (unswizzled)
//   [67,108,864, 100,663,296)  pre_f bf16 (32768 x 512)  [cell][gate] layout
//   [100,663,296,134,217,728)  pre_b bf16 (32768 x 512)  [cell][gate] layout
//   [134,217,728,134,742,016)  gz0, gz1, smax, z (32768 fp32 each)
//   [134,742,016,135,790,592)  w1f bf16 (512x1024) SWIZZLED
//   [135,790,592,136,839,168)  w1b bf16            SWIZZLED
//   [136,839,168,137,101,312)  w2f bf16 (512x256)  linear
//   [137,101,312,137,363,456)  w2b bf16            linear
//   [137,363,456,137,371,648)  bs[4][512] fp32 (bih+bhh, l1f/l1b/l2f/l2b)
//
// SWIZZLE (g, w1f, w1b; rule #21 both-sides): rows of 1024 bf16 = 128 chunks
// of 8 bf16 (16B). Element (row, col): stored chunk = (col>>3) with LOW 3 BITS
// XOR'd by (row&7). gemm1 stages linearly via global_load_lds (LDS [128][64],
// no pad) and applies the same XOR on the ds_read address -> conflict-free.

typedef short short8v __attribute__((ext_vector_type(8)));
typedef float f32x4 __attribute__((ext_vector_type(4)));
typedef unsigned short ushort8v __attribute__((ext_vector_type(8)));
typedef unsigned short ushort4v __attribute__((ext_vector_type(4)));

static __device__ __forceinline__ float bf2f(unsigned short u) {
  return __uint_as_float(((unsigned int)u) << 16);
}
static __device__ __forceinline__ unsigned short f2bf(float f) {  // RNE
  unsigned int u = __float_as_uint(f);
  return (unsigned short)((u + 0x7FFFu + ((u >> 16) & 1u)) >> 16);
}
static __device__ __forceinline__ float fsig(float x) {
  return 1.f / (1.f + __expf(-x));
}
static __device__ __forceinline__ float ftanh(float x) {
  return 1.f - 2.f / (__expf(2.f * x) + 1.f);
}
// swizzled column (in shorts) for logical (row, col) in a 1024-wide row
static __device__ __forceinline__ int swzcol(int row, int col) {
  int ch = col >> 3;
  int cs = (ch & ~7) | ((ch ^ row) & 7);
  return cs * 8 + (col & 7);
}
static __device__ __forceinline__ void gld_lds16(const void* g, void* l) {
  __builtin_amdgcn_global_load_lds(
      (const __attribute__((address_space(1))) unsigned int*)g,
      (__attribute__((address_space(3))) unsigned int*)l, 16, 0, 0);
}

// ---------------- weight pre-convert: 4x Wih fp32->bf16, bias sums ----------
// w1f/w1b written SWIZZLED; w2f/w2b linear.
__global__ __launch_bounds__(256) void cvt_w_kernel(
    const float* __restrict__ w1f, const float* __restrict__ w1b,
    const float* __restrict__ w2f, const float* __restrict__ w2b,
    const float* __restrict__ b1fi, const float* __restrict__ b1fh,
    const float* __restrict__ b1bi, const float* __restrict__ b1bh,
    const float* __restrict__ b2fi, const float* __restrict__ b2fh,
    const float* __restrict__ b2bi, const float* __restrict__ b2bh,
    unsigned short* __restrict__ d1f, unsigned short* __restrict__ d1b,
    unsigned short* __restrict__ d2f, unsigned short* __restrict__ d2b,
    float* __restrict__ bs)
{
  const int bid = blockIdx.x, tid = threadIdx.x;
  if (bid < 1280) {
    int idx = (bid * 256 + tid) * 4;
    const float* src;
    unsigned short* dst;
    int off;
    bool swz;
    if (idx < 524288)        { src = w1f; dst = d1f; off = idx; swz = true; }
    else if (idx < 1048576)  { src = w1b; dst = d1b; off = idx - 524288; swz = true; }
    else if (idx < 1179648)  { src = w2f; dst = d2f; off = idx - 1048576; swz = false; }
    else                     { src = w2b; dst = d2b; off = idx - 1179648; swz = false; }
    float4 f = *(const float4*)(src + off);
    ushort4v v;
    v[0] = f2bf(f.x); v[1] = f2bf(f.y); v[2] = f2bf(f.z); v[3] = f2bf(f.w);
    if (swz) {
      int row = off >> 10, col = off & 1023;
      *(ushort4v*)(dst + ((size_t)row << 10) + swzcol(row, col)) = v;
    } else {
      *(ushort4v*)(dst + off) = v;
    }
  } else {
    int bidx = (bid - 1280) * 256 + tid;   // 0..2047
    int which = bidx >> 9, col = bidx & 511;
    float v;
    if (which == 0)      v = b1fi[col] + b1fh[col];
    else if (which == 1) v = b1bi[col] + b1bh[col];
    else if (which == 2) v = b2fi[col] + b2fh[col];
    else                 v = b2bi[col] + b2bh[col];
    bs[bidx] = v;
  }
}

// ---------------- MFMA attention (r11 winner; g writes swizzled) --------
__global__ __launch_bounds__(256) void attn_kernel(
    const float* __restrict__ c, const float* __restrict__ q,
    const float* __restrict__ wc, const float* __restrict__ bc,
    const float* __restrict__ wq, const float* __restrict__ bq,
    const float* __restrict__ wcq, const float* __restrict__ bcq,
    const float* __restrict__ W0, const float* __restrict__ W1,
    __hip_bfloat16* __restrict__ g, float* __restrict__ smax,
    float* __restrict__ gz0, float* __restrict__ gz1)
{
  __shared__ unsigned short cbf[128][264];  // c bf16 (A for S; cv in epilogue)
  __shared__ unsigned short qhb[64][264];   // qhat bf16 j-major (B for S)
  __shared__ unsigned short qtb[256][72];   // q bf16 d-major (B for c2q)
  __shared__ unsigned short Pbuf[4][16][72];// per-wave P transpose (A for c2q)
  __shared__ float qwqs[64];
  __shared__ float qwp[4][64];
  const int b = blockIdx.x, tid = threadIdx.x;
  const int wave = tid >> 6, lane = tid & 63;
  const int t0 = blockIdx.y * 128;
  unsigned short* gbase = (unsigned short*)g;

  #pragma unroll
  for (int i = 0; i < 16; ++i) {
    int idx = tid + i * 256;               // 4096 float4
    int j = idx >> 6, d4 = (idx & 63) * 4;
    float4 v = *(const float4*)&q[((size_t)b * 64 + j) * 256 + d4];
    float4 w4 = *(const float4*)&wcq[d4];
    float4 c4 = *(const float4*)&wc[d4];
    qhb[j][d4 + 0] = f2bf(v.x * w4.x + c4.x);
    qhb[j][d4 + 1] = f2bf(v.y * w4.y + c4.y);
    qhb[j][d4 + 2] = f2bf(v.z * w4.z + c4.z);
    qhb[j][d4 + 3] = f2bf(v.w * w4.w + c4.w);
    qtb[d4 + 0][j] = f2bf(v.x);
    qtb[d4 + 1][j] = f2bf(v.y);
    qtb[d4 + 2][j] = f2bf(v.z);
    qtb[d4 + 3][j] = f2bf(v.w);
  }
  #pragma unroll
  for (int i = 0; i < 32; ++i) {
    int idx = tid + i * 256;               // 8192 float4
    int r = idx >> 6, d4 = (idx & 63) * 4;
    float4 v = *(const float4*)&c[((size_t)b * 512 + t0 + r) * 256 + d4];
    ushort4v u;
    u[0] = f2bf(v.x); u[1] = f2bf(v.y); u[2] = f2bf(v.z); u[3] = f2bf(v.w);
    *(ushort4v*)&cbf[r][d4] = u;
    *(ushort4v*)&gbase[((size_t)b * 512 + t0 + r) * 1024 + swzcol(r, d4)] = u;
  }
  __syncthreads();
  {
    float s = 0.f;
    for (int dd = 0; dd < 64; ++dd) {
      int d = wave * 64 + dd;
      s += bf2f(qtb[d][lane]) * wq[d];
    }
    qwp[wave][lane] = s;
  }
  __syncthreads();
  if (tid < 64) qwqs[tid] = qwp[0][tid] + qwp[1][tid] + qwp[2][tid] + qwp[3][tid] + bq[0];
  __syncthreads();

  const int cl = lane & 15, kg = lane >> 4;
  const float sbias = bc[0] + bcq[0];

  #pragma unroll
  for (int half = 0; half < 2; ++half) {
    const int tt = wave + half * 4;
    const int rowb = tt * 16;
    f32x4 acc[4] = {};
    #pragma unroll
    for (int kt = 0; kt < 8; ++kt) {
      short8v a = *(const short8v*)&cbf[rowb + cl][kt * 32 + kg * 8];
      #pragma unroll
      for (int jt = 0; jt < 4; ++jt) {
        short8v bq_ = *(const short8v*)&qhb[jt * 16 + cl][kt * 32 + kg * 8];
        acc[jt] = __builtin_amdgcn_mfma_f32_16x16x32_bf16(a, bq_, acc[jt], 0, 0, 0);
      }
    }
    #pragma unroll
    for (int jt = 0; jt < 4; ++jt) {
      float qadd = qwqs[jt * 16 + cl] + sbias;
      #pragma unroll
      for (int r = 0; r < 4; ++r) acc[jt][r] += qadd;
    }
    f32x4 mx = acc[0];
    #pragma unroll
    for (int jt = 1; jt < 4; ++jt)
      #pragma unroll
      for (int r = 0; r < 4; ++r) mx[r] = fmaxf(mx[r], acc[jt][r]);
    #pragma unroll
    for (int off = 1; off < 16; off <<= 1)
      #pragma unroll
      for (int r = 0; r < 4; ++r) mx[r] = fmaxf(mx[r], __shfl_xor(mx[r], off));
    f32x4 se = {0.f, 0.f, 0.f, 0.f};
    #pragma unroll
    for (int jt = 0; jt < 4; ++jt)
      #pragma unroll
      for (int r = 0; r < 4; ++r) {
        acc[jt][r] = __expf(acc[jt][r] - mx[r]);
        se[r] += acc[jt][r];
      }
    #pragma unroll
    for (int off = 1; off < 16; off <<= 1)
      #pragma unroll
      for (int r = 0; r < 4; ++r) se[r] += __shfl_xor(se[r], off);
    f32x4 inv;
    #pragma unroll
    for (int r = 0; r < 4; ++r) inv[r] = 1.f / se[r];
    #pragma unroll
    for (int jt = 0; jt < 4; ++jt)
      #pragma unroll
      for (int r = 0; r < 4; ++r)
        Pbuf[wave][4 * kg + r][jt * 16 + cl] = f2bf(acc[jt][r] * inv[r]);
    if (cl == 0) {
      #pragma unroll
      for (int r = 0; r < 4; ++r)
        smax[(size_t)b * 512 + t0 + rowb + 4 * kg + r] = mx[r];
    }
    f32x4 gz0p = {0.f, 0.f, 0.f, 0.f}, gz1p = {0.f, 0.f, 0.f, 0.f};
    for (int dt = 0; dt < 16; ++dt) {
      f32x4 ca = {0.f, 0.f, 0.f, 0.f};
      #pragma unroll
      for (int kt = 0; kt < 2; ++kt) {
        short8v pa = *(const short8v*)&Pbuf[wave][cl][kt * 32 + kg * 8];
        short8v qb_ = *(const short8v*)&qtb[dt * 16 + cl][kt * 32 + kg * 8];
        ca = __builtin_amdgcn_mfma_f32_16x16x32_bf16(pa, qb_, ca, 0, 0, 0);
      }
      int d = dt * 16 + cl;
      float w0a = W0[d], w0b_ = W0[256 + d], w0c2 = W0[512 + d];
      float w1a = W1[d], w1b2 = W1[256 + d], w1c2 = W1[512 + d];
      #pragma unroll
      for (int r = 0; r < 4; ++r) {
        int rloc = rowb + 4 * kg + r;
        float cv = bf2f(cbf[rloc][d]);
        float av = ca[r];
        float pr = cv * av;
        size_t gr = ((size_t)b * 512 + t0 + rloc) * 1024;
        gbase[gr + swzcol(rloc, 256 + d)] = f2bf(av);
        gbase[gr + swzcol(rloc, 512 + d)] = f2bf(pr);
        gz0p[r] += cv * w0a + av * w0b_ + pr * w0c2;
        gz1p[r] += cv * w1a + av * w1b2 + pr * w1c2;
      }
    }
    #pragma unroll
    for (int off = 1; off < 16; off <<= 1)
      #pragma unroll
      for (int r = 0; r < 4; ++r) {
        gz0p[r] += __shfl_xor(gz0p[r], off);
        gz1p[r] += __shfl_xor(gz1p[r], off);
      }
    if (cl == 0) {
      #pragma unroll
      for (int r = 0; r < 4; ++r) {
        size_t rw = (size_t)b * 512 + t0 + rowb + 4 * kg + r;
        gz0[rw] = gz0p[r];
        gz1[rw] = gz1p[r];
      }
    }
  }
}

// ---------------- b_att softmax over t, q2c, g[768:1024] (swizzled), gz tail ----
__global__ __launch_bounds__(256) void batt_kernel(
    const float* __restrict__ c, const float* __restrict__ smax,
    const float* __restrict__ W0, const float* __restrict__ W1,
    __hip_bfloat16* __restrict__ g,
    float* __restrict__ gz0, float* __restrict__ gz1)
{
  __shared__ float sm[512];
  __shared__ float red[4], red2[4];
  __shared__ float q2c_s[256];
  const int b = blockIdx.x, tid = threadIdx.x;
  float v0 = smax[(size_t)b * 512 + tid];
  float v1 = smax[(size_t)b * 512 + tid + 256];
  float m = fmaxf(v0, v1);
  #pragma unroll
  for (int off = 32; off; off >>= 1) m = fmaxf(m, __shfl_xor(m, off));
  if ((tid & 63) == 0) red[tid >> 6] = m;
  __syncthreads();
  float M = fmaxf(fmaxf(red[0], red[1]), fmaxf(red[2], red[3]));
  float e0 = expf(v0 - M), e1 = expf(v1 - M);
  float ssum = e0 + e1;
  #pragma unroll
  for (int off = 32; off; off >>= 1) ssum += __shfl_xor(ssum, off);
  if ((tid & 63) == 0) red2[tid >> 6] = ssum;
  __syncthreads();
  float S = red2[0] + red2[1] + red2[2] + red2[3];
  sm[tid] = e0 / S;
  sm[tid + 256] = e1 / S;
  __syncthreads();
  float acc = 0.f;
  #pragma unroll 8
  for (int t = 0; t < 512; ++t) acc += sm[t] * c[((size_t)b * 512 + t) * 256 + tid];
  q2c_s[tid] = acc;
  __syncthreads();
  const int wave = tid >> 6, lane = tid & 63;
  float qv[4], w0c[4], w1c[4];
  #pragma unroll
  for (int r = 0; r < 4; ++r) {
    int d = lane + 64 * r;
    qv[r]  = q2c_s[d];
    w0c[r] = W0[768 + d];
    w1c[r] = W1[768 + d];
  }
  for (int t = wave; t < 512; t += 4) {
    size_t row = (size_t)b * 512 + t;
    float s0 = 0.f, s1 = 0.f;
    #pragma unroll
    for (int r = 0; r < 4; ++r) {
      int d = lane + 64 * r;
      float v = c[row * 256 + d];
      float gv = v * qv[r];
      g[row * 1024 + swzcol(t, 768 + d)] = __float2bfloat16(gv);
      s0 += gv * w0c[r];
      s1 += gv * w1c[r];
    }
    #pragma unroll
    for (int off = 32; off; off >>= 1) {
      s0 += __shfl_xor(s0, off);
      s1 += __shfl_xor(s1, off);
    }
    if (lane == 0) { gz0[row] += s0; gz1[row] += s1; }
  }
}

// ---------------- gemm1: pre = g_swz @ W_swz^T + bs, via global_load_lds -------
__global__ __launch_bounds__(256) void gemm1_kernel(
    const unsigned short* __restrict__ X,
    const unsigned short* __restrict__ Wf, const unsigned short* __restrict__ Wb,
    const float* __restrict__ bsf, const float* __restrict__ bsb,
    __hip_bfloat16* __restrict__ Yf, __hip_bfloat16* __restrict__ Yb)
{
  __shared__ unsigned short Xs[128 * 64];
  __shared__ unsigned short Ws[128 * 64];
  const unsigned short* W = blockIdx.z ? Wb : Wf;
  const float* bs = blockIdx.z ? bsb : bsf;
  __hip_bfloat16* Y = blockIdx.z ? Yb : Yf;
  const int tid = threadIdx.x;
  const int m0 = blockIdx.x * 128, n0 = blockIdx.y * 128;
  const int lane = tid & 63, wave = tid >> 6;
  const int wr = wave >> 1, wc = wave & 1;
  const int frow = lane & 15, kg = lane >> 4;
  const int r7 = frow & 7;
  const int cid_l = wave * 64 + lane;

  f32x4 acc[4][4] = {};
  for (int kt = 0; kt < 1024; kt += 64) {
    #pragma unroll
    for (int i = 0; i < 4; ++i) {
      int cb = i * 256 + wave * 64;
      int cid = i * 256 + cid_l;
      int row = cid >> 3, ch = cid & 7;
      gld_lds16(X + (size_t)(m0 + row) * 1024 + kt + ch * 8, Xs + cb * 8);
      gld_lds16(W + (size_t)(n0 + row) * 1024 + kt + ch * 8, Ws + cb * 8);
    }
    __syncthreads();
    #pragma unroll
    for (int kk = 0; kk < 64; kk += 32) {
      const int pc = (((kk >> 3) + kg) ^ r7) * 8;
      short8v a[4], bfr[4];
      #pragma unroll
      for (int i = 0; i < 4; ++i)
        a[i] = *(const short8v*)&Xs[(wr * 64 + i * 16 + frow) * 64 + pc];
      #pragma unroll
      for (int j = 0; j < 4; ++j)
        bfr[j] = *(const short8v*)&Ws[(wc * 64 + j * 16 + frow) * 64 + pc];
      #pragma unroll
      for (int i = 0; i < 4; ++i)
        #pragma unroll
        for (int j = 0; j < 4; ++j)
          acc[i][j] = __builtin_amdgcn_mfma_f32_16x16x32_bf16(a[i], bfr[j], acc[i][j], 0, 0, 0);
    }
    __syncthreads();
  }
  const int r0 = kg * 4;
  #pragma unroll
  for (int j = 0; j < 4; ++j) {
    int col = n0 + wc * 64 + j * 16 + frow;
    int colp = (col & 127) * 4 + (col >> 7);
    float bsum = bs[col];
    #pragma unroll
    for (int i = 0; i < 4; ++i) {
      int rowb = m0 + wr * 64 + i * 16 + r0;
      #pragma unroll
      for (int r = 0; r < 4; ++r)
        Y[(size_t)(rowb + r) * 512 + colp] = __float2bfloat16(acc[i][j][r] + bsum);
    }
  }
}

// ---------------- MFMA GEMM (layer 2, linear W/m; unchanged) ------
__global__ __launch_bounds__(256) void gemm_mfma_kernel(
    const __hip_bfloat16* __restrict__ Xg,
    const unsigned short* __restrict__ Wf, const unsigned short* __restrict__ Wb,
    const float* __restrict__ bsf, const float* __restrict__ bsb,
    __hip_bfloat16* __restrict__ Yf, __hip_bfloat16* __restrict__ Yb, int K)
{
  __shared__ unsigned short Xs[128 * 72];
  __shared__ unsigned short Ws[128 * 72];
  const unsigned short* X = (const unsigned short*)Xg;
  const unsigned short* W = blockIdx.z ? Wb : Wf;
  const float* bs = blockIdx.z ? bsb : bsf;
  __hip_bfloat16* Y = blockIdx.z ? Yb : Yf;
  const int tid = threadIdx.x;
  const int m0 = blockIdx.x * 128, n0 = blockIdx.y * 128;
  const int lane = tid & 63, wave = tid >> 6;
  const int wr = wave >> 1, wc = wave & 1;
  const int frow = lane & 15, fk = (lane >> 4) * 8;

  f32x4 acc[4][4] = {};
  for (int kt = 0; kt < K; kt += 64) {
    #pragma unroll
    for (int i = 0; i < 4; ++i) {
      int cidx = tid + 256 * i;
      int row = cidx >> 3, kc = cidx & 7;
      *(ushort8v*)&Xs[row * 72 + kc * 8] =
          *(const ushort8v*)&X[(size_t)(m0 + row) * K + kt + kc * 8];
      *(ushort8v*)&Ws[row * 72 + kc * 8] =
          *(const ushort8v*)&W[(size_t)(n0 + row) * K + kt + kc * 8];
    }
    __syncthreads();
    #pragma unroll
    for (int kk = 0; kk < 64; kk += 32) {
      short8v a[4], bfr[4];
      #pragma unroll
      for (int i = 0; i < 4; ++i)
        a[i] = *(const short8v*)&Xs[(wr * 64 + i * 16 + frow) * 72 + kk + fk];
      #pragma unroll
      for (int j = 0; j < 4; ++j)
        bfr[j] = *(const short8v*)&Ws[(wc * 64 + j * 16 + frow) * 72 + kk + fk];
      #pragma unroll
      for (int i = 0; i < 4; ++i)
        #pragma unroll
        for (int j = 0; j < 4; ++j)
          acc[i][j] = __builtin_amdgcn_mfma_f32_16x16x32_bf16(a[i], bfr[j], acc[i][j], 0, 0, 0);
    }
    __syncthreads();
  }
  const int r0 = (lane >> 4) * 4;
  #pragma unroll
  for (int j = 0; j < 4; ++j) {
    int col = n0 + wc * 64 + j * 16 + (lane & 15);
    int colp = (col & 127) * 4 + (col >> 7);
    float bsum = bs[col];
    #pragma unroll
    for (int i = 0; i < 4; ++i) {
      int rowb = m0 + wr * 64 + i * 16 + r0;
      #pragma unroll
      for (int r = 0; r < 4; ++r)
        Y[(size_t)(rowb + r) * 512 + colp] = __float2bfloat16(acc[i][j][r] + bsum);
    }
  }
}

// ---------------- LSTM recurrence via MFMA, 8-step chunked I/O ----------------
// r14 change (ONLY): __syncthreads() -> s_waitcnt lgkmcnt(0) + raw s_barrier.
// LDS h-visibility needs only lgkmcnt; the chunk's pre-loads / h-stores stay
// in flight across barriers (no per-step vmcnt(0) drain). NO sched_barrier
// pins (r7's mistake). Everything else identical to the r10/r13 winner.
__global__ __launch_bounds__(512, 2) void lstm_kernel(
    const __hip_bfloat16* __restrict__ pre_f, const __hip_bfloat16* __restrict__ pre_b,
    const float* __restrict__ Whh_f, const float* __restrict__ Whh_b,
    __hip_bfloat16* __restrict__ out)
{
  const int b = blockIdx.x, dir = blockIdx.y;
  const unsigned short* __restrict__ pre =
      (const unsigned short*)(dir ? pre_b : pre_f);
  const float* __restrict__ Whh = dir ? Whh_b : Whh_f;
  const int off = dir ? 128 : 0;
  const int tid = threadIdx.x;
  const int wave = tid >> 6, lane = tid & 63;
  const int cl = lane & 15;            // col / cell-within-wave
  const int kg = lane >> 4;            // k-group 0..3
  const int cell = wave * 16 + cl;     // 0..127

#define LOAD_BF(Q, T, DST)                                            \
  {                                                                   \
    const float* wp = Whh + (size_t)(Q * 128 + cell) * 128 + T * 32 + kg * 8; \
    float4 f0 = *(const float4*)wp;                                   \
    float4 f1 = *(const float4*)(wp + 4);                             \
    DST[0] = (short)f2bf(f0.x); DST[1] = (short)f2bf(f0.y);           \
    DST[2] = (short)f2bf(f0.z); DST[3] = (short)f2bf(f0.w);           \
    DST[4] = (short)f2bf(f1.x); DST[5] = (short)f2bf(f1.y);           \
    DST[6] = (short)f2bf(f1.z); DST[7] = (short)f2bf(f1.w);           \
    asm volatile("" : "+v"(DST));                                     \
  }
  short8v bf00, bf01, bf02, bf03, bf10, bf11, bf12, bf13;
  short8v bf20, bf21, bf22, bf23, bf30, bf31, bf32, bf33;
  LOAD_BF(0, 0, bf00) LOAD_BF(0, 1, bf01) LOAD_BF(0, 2, bf02) LOAD_BF(0, 3, bf03)
  LOAD_BF(1, 0, bf10) LOAD_BF(1, 1, bf11) LOAD_BF(1, 2, bf12) LOAD_BF(1, 3, bf13)
  LOAD_BF(2, 0, bf20) LOAD_BF(2, 1, bf21) LOAD_BF(2, 2, bf22) LOAD_BF(2, 3, bf23)
  LOAD_BF(3, 0, bf30) LOAD_BF(3, 1, bf31) LOAD_BF(3, 2, bf32) LOAD_BF(3, 3, bf33)
#undef LOAD_BF

  __shared__ unsigned short hbuf[2][128];
  if (tid < 128) { hbuf[0][tid] = 0; hbuf[1][tid] = 0; }
  __syncthreads();

  const size_t base = (size_t)b * 512;
  const int tstep = dir ? -1 : 1;
  const int t0 = dir ? 511 : 0;
  const unsigned short* prow = pre + base * 512 + cell * 4;
  unsigned short* orow = (unsigned short*)out + base * 256 + off + cell;

  int cur = 0;
  float cst = 0.f;
  f32x4 acc0 = {0.f, 0.f, 0.f, 0.f};
  f32x4 acc1 = acc0, acc2 = acc0, acc3 = acc0;

#define LSTM_STEP(P, HOUT)                                                  \
  {                                                                         \
    const unsigned short* hb = hbuf[cur];                                   \
    short8v a0 = *(const short8v*)(hb +  0 + kg * 8);                       \
    short8v a1 = *(const short8v*)(hb + 32 + kg * 8);                       \
    short8v a2 = *(const short8v*)(hb + 64 + kg * 8);                       \
    short8v a3 = *(const short8v*)(hb + 96 + kg * 8);                       \
    acc0[0] = bf2f(P[0]); acc1[0] = bf2f(P[1]);                             \
    acc2[0] = bf2f(P[2]); acc3[0] = bf2f(P[3]);                             \
    acc0 = __builtin_amdgcn_mfma_f32_16x16x32_bf16(a0, bf00, acc0, 0, 0, 0);\
    acc1 = __builtin_amdgcn_mfma_f32_16x16x32_bf16(a0, bf10, acc1, 0, 0, 0);\
    acc2 = __builtin_amdgcn_mfma_f32_16x16x32_bf16(a0, bf20, acc2, 0, 0, 0);\
    acc3 = __builtin_amdgcn_mfma_f32_16x16x32_bf16(a0, bf30, acc3, 0, 0, 0);\
    acc0 = __builtin_amdgcn_mfma_f32_16x16x32_bf16(a1, bf01, acc0, 0, 0, 0);\
    acc1 = __builtin_amdgcn_mfma_f32_16x16x32_bf16(a1, bf11, acc1, 0, 0, 0);\
    acc2 = __builtin_amdgcn_mfma_f32_16x16x32_bf16(a1, bf21, acc2, 0, 0, 0);\
    acc3 = __builtin_amdgcn_mfma_f32_16x16x32_bf16(a1, bf31, acc3, 0, 0, 0);\
    acc0 = __builtin_amdgcn_mfma_f32_16x16x32_bf16(a2, bf02, acc0, 0, 0, 0);\
    acc1 = __builtin_amdgcn_mfma_f32_16x16x32_bf16(a2, bf12, acc1, 0, 0, 0);\
    acc2 = __builtin_amdgcn_mfma_f32_16x16x32_bf16(a2, bf22, acc2, 0, 0, 0);\
    acc3 = __builtin_amdgcn_mfma_f32_16x16x32_bf16(a2, bf32, acc3, 0, 0, 0);\
    acc0 = __builtin_amdgcn_mfma_f32_16x16x32_bf16(a3, bf03, acc0, 0, 0, 0);\
    acc1 = __builtin_amdgcn_mfma_f32_16x16x32_bf16(a3, bf13, acc1, 0, 0, 0);\
    acc2 = __builtin_amdgcn_mfma_f32_16x16x32_bf16(a3, bf23, acc2, 0, 0, 0);\
    acc3 = __builtin_amdgcn_mfma_f32_16x16x32_bf16(a3, bf33, acc3, 0, 0, 0);\
    float gi_ = fsig(acc0[0]);                                              \
    float gf_ = fsig(acc1[0]);                                              \
    float gg_ = ftanh(acc2[0]);                                             \
    float go_ = fsig(acc3[0]);                                              \
    cst = gf_ * cst + gi_ * gg_;                                            \
    float hv = go_ * ftanh(cst);                                            \
    HOUT = f2bf(hv);                                                        \
    if (lane < 16) hbuf[cur ^ 1][cell] = HOUT;                              \
    asm volatile("s_waitcnt lgkmcnt(0)" ::: "memory");                      \
    __builtin_amdgcn_s_barrier();                                           \
    cur ^= 1;                                                               \
  }

  for (int chunk = 0; chunk < 64; ++chunk) {
    const int tb = t0 + chunk * 8 * tstep;
    ushort4v p0 = *(const ushort4v*)(prow + (size_t)(tb)             * 512);
    ushort4v p1 = *(const ushort4v*)(prow + (size_t)(tb + 1 * tstep) * 512);
    ushort4v p2 = *(const ushort4v*)(prow + (size_t)(tb + 2 * tstep) * 512);
    ushort4v p3 = *(const ushort4v*)(prow + (size_t)(tb + 3 * tstep) * 512);
    ushort4v p4 = *(const ushort4v*)(prow + (size_t)(tb + 4 * tstep) * 512);
    ushort4v p5 = *(const ushort4v*)(prow + (size_t)(tb + 5 * tstep) * 512);
    ushort4v p6 = *(const ushort4v*)(prow + (size_t)(tb + 6 * tstep) * 512);
    ushort4v p7 = *(const ushort4v*)(prow + (size_t)(tb + 7 * tstep) * 512);
    unsigned short h0, h1, h2, h3, h4, h5, h6, h7;
    LSTM_STEP(p0, h0)
    LSTM_STEP(p1, h1)
    LSTM_STEP(p2, h2)
    LSTM_STEP(p3, h3)
    LSTM_STEP(p4, h4)
    LSTM_STEP(p5, h5)
    LSTM_STEP(p6, h6)
    LSTM_STEP(p7, h7)
    if (lane < 16) {
      orow[(size_t)(tb)             * 256] = h0;
      orow[(size_t)(tb + 1 * tstep) * 256] = h1;
      orow[(size_t)(tb + 2 * tstep) * 256] = h2;
      orow[(size_t)(tb + 3 * tstep) * 256] = h3;
      orow[(size_t)(tb + 4 * tstep) * 256] = h4;
      orow[(size_t)(tb + 5 * tstep) * 256] = h5;
      orow[(size_t)(tb + 6 * tstep) * 256] = h6;
      orow[(size_t)(tb + 7 * tstep) * 256] = h7;
    }
  }
#undef LSTM_STEP
}

// ---------------- logits: z[row] = gz[row] + m_row(bf16) . W[1024:1280] + bias ----
__global__ __launch_bounds__(256) void logits_kernel(
    const __hip_bfloat16* __restrict__ m, const float* __restrict__ W,
    const float* __restrict__ bias, const float* __restrict__ gz,
    float* __restrict__ z)
{
  const int row = blockIdx.x * 4 + (threadIdx.x >> 6);
  const int lane = threadIdx.x & 63;
  const unsigned short* mrow = (const unsigned short*)m + (size_t)row * 256;
  float acc = 0.f;
  #pragma unroll
  for (int i = 0; i < 4; ++i) acc += bf2f(mrow[lane + 64 * i]) * W[1024 + lane + 64 * i];
  #pragma unroll
  for (int off = 32; off; off >>= 1) acc += __shfl_xor(acc, off);
  if (lane == 0) z[row] = acc + gz[row] + bias[0];
}

// ---------------- softmax over t ----------------
__global__ __launch_bounds__(512) void softmax_t_kernel(
    const float* __restrict__ z, float* __restrict__ p)
{
  const int b = blockIdx.x, t = threadIdx.x;
  __shared__ float red[8], red2[8];
  float v = z[(size_t)b * 512 + t];
  float m = v;
  #pragma unroll
  for (int off = 32; off; off >>= 1) m = fmaxf(m, __shfl_xor(m, off));
  if ((t & 63) == 0) red[t >> 6] = m;
  __syncthreads();
  float M = red[0];
  #pragma unroll
  for (int i = 1; i < 8; ++i) M = fmaxf(M, red[i]);
  float e = expf(v - M);
  float s = e;
  #pragma unroll
  for (int off = 32; off; off >>= 1) s += __shfl_xor(s, off);
  if ((t & 63) == 0) red2[t >> 6] = s;
  __syncthreads();
  float S = red2[0];
  #pragma unroll
  for (int i = 1; i < 8; ++i) S += red2[i];
  p[(size_t)b * 512 + t] = e / S;
}

extern "C" void kernel_launch(void* const* d_in, const int* in_sizes, int n_in,
                              void* d_out, int out_size, void* d_ws, size_t ws_size,
                              hipStream_t stream)
{
  const float* c   = (const float*)d_in[0];
  const float* q   = (const float*)d_in[1];
  const float* wc  = (const float*)d_in[2];
  const float* bc  = (const float*)d_in[3];
  const float* wq  = (const float*)d_in[4];
  const float* bq  = (const float*)d_in[5];
  const float* wcq = (const float*)d_in[6];
  const float* bcq = (const float*)d_in[7];
  const float* l1f_Wih = (const float*)d_in[8];
  const float* l1f_Whh = (const float*)d_in[9];
  const float* l1f_bih = (const float*)d_in[10];
  const float* l1f_bhh = (const float*)d_in[11];
  const float* l1b_Wih = (const float*)d_in[12];
  const float* l1b_Whh = (const float*)d_in[13];
  const float* l1b_bih = (const float*)d_in[14];
  const float* l1b_bhh = (const float*)d_in[15];
  const float* l2f_Wih = (const float*)d_in[16];
  const float* l2f_Whh = (const float*)d_in[17];
  const float* l2f_bih = (const float*)d_in[18];
  const float* l2f_bhh = (const float*)d_in[19];
  const float* l2b_Wih = (const float*)d_in[20];
  const float* l2b_Whh = (const float*)d_in[21];
  const float* l2b_bih = (const float*)d_in[22];
  const float* l2b_bhh = (const float*)d_in[23];
  const float* W0 = (const float*)d_in[24];
  const float* b0 = (const float*)d_in[25];
  const float* W1 = (const float*)d_in[26];
  const float* b1 = (const float*)d_in[27];

  const size_t required = 137371648u;
  if (ws_size < required) return;

  char* wsb = (char*)d_ws;
  __hip_bfloat16* gbf = (__hip_bfloat16*)wsb;
  __hip_bfloat16* m   = (__hip_bfloat16*)wsb;
  __hip_bfloat16* m2  = (__hip_bfloat16*)(wsb + 33554432);
  __hip_bfloat16* pref = (__hip_bfloat16*)(wsb + 67108864);
  __hip_bfloat16* preb = (__hip_bfloat16*)(wsb + 100663296);
  float* gz0  = (float*)(wsb + 134217728);
  float* gz1  = gz0 + 32768;
  float* smax = gz1 + 32768;
  float* z    = smax + 32768;
  unsigned short* w1f = (unsigned short*)(wsb + 134742016);
  unsigned short* w1b = (unsigned short*)(wsb + 135790592);
  unsigned short* w2f = (unsigned short*)(wsb + 136839168);
  unsigned short* w2b = (unsigned short*)(wsb + 137101312);
  float* bs = (float*)(wsb + 137363456);
  float* p1 = (float*)d_out;
  float* p2 = p1 + 32768;

  cvt_w_kernel<<<1288, 256, 0, stream>>>(l1f_Wih, l1b_Wih, l2f_Wih, l2b_Wih,
                                         l1f_bih, l1f_bhh, l1b_bih, l1b_bhh,
                                         l2f_bih, l2f_bhh, l2b_bih, l2b_bhh,
                                         w1f, w1b, w2f, w2b, bs);
  attn_kernel<<<dim3(64, 4), 256, 0, stream>>>(c, q, wc, bc, wq, bq, wcq, bcq,
                                               W0, W1, gbf, smax, gz0, gz1);
  batt_kernel<<<64, 256, 0, stream>>>(c, smax, W0, W1, gbf, gz0, gz1);

  gemm1_kernel<<<dim3(256, 4, 2), 256, 0, stream>>>(
      (const unsigned short*)gbf, w1f, w1b, bs, bs + 512, pref, preb);
  lstm_kernel<<<dim3(64, 2), 512, 0, stream>>>(pref, preb, l1f_Whh, l1b_Whh, m);

  logits_kernel<<<8192, 256, 0, stream>>>(m, W0, b0, gz0, z);
  softmax_t_kernel<<<64, 512, 0, stream>>>(z, p1);

  gemm_mfma_kernel<<<dim3(256, 4, 2), 256, 0, stream>>>(
      m, w2f, w2b, bs + 1024, bs + 1536, pref, preb, 256);
  lstm_kernel<<<dim3(64, 2), 512, 0, stream>>>(pref, preb, l2f_Whh, l2b_Whh, m2);

  logits_kernel<<<8192, 256, 0, stream>>>(m2, W1, b1, gz1, z);
  softmax_t_kernel<<<64, 512, 0, stream>>>(z, p2);
}

// Round 15
// 956.255 us; speedup vs baseline: 1.6268x; 1.0008x over previous
//
#include <hip/hip_runtime.h>
#include <hip/hip_bf16.h>
#include <cstdint>
#include <cstddef>

// Shapes: B=64, T=512, J=64, D=256, E=128, gdim=8E=1024, gates=4E=512
// ws layout (bytes), total 137,371,648 (~131 MiB):
//   [0,           67,108,864)  g bf16 (32768 x 1024)  SWIZZLED (see below)
//        aliased: m  bf16 (32768 x 256) at 0 ; m2 bf16 at 33,554,432 (unswizzled)
//   [67,108,864, 100,663,296)  pre_f bf16 (32768 x 512)  [cell][gate] layout
//   [100,663,296,134,217,728)  pre_b bf16 (32768 x 512)  [cell][gate] layout
//   [134,217,728,134,742,016)  gz0, gz1, smax, z (32768 fp32 each)
//   [134,742,016,135,790,592)  w1f bf16 (512x1024) SWIZZLED
//   [135,790,592,136,839,168)  w1b bf16            SWIZZLED
//   [136,839,168,137,101,312)  w2f bf16 (512x256)  linear
//   [137,101,312,137,363,456)  w2b bf16            linear
//   [137,363,456,137,371,648)  bs[4][512] fp32 (bih+bhh, l1f/l1b/l2f/l2b)
//
// SWIZZLE (g, w1f, w1b; rule #21 both-sides): rows of 1024 bf16 = 128 chunks
// of 8 bf16 (16B). Element (row, col): stored chunk = (col>>3) with LOW 3 BITS
// XOR'd by (row&7). gemm1 stages linearly via global_load_lds (LDS [128][64],
// no pad) and applies the same XOR on the ds_read address -> conflict-free.

typedef short short8v __attribute__((ext_vector_type(8)));
typedef float f32x4 __attribute__((ext_vector_type(4)));
typedef unsigned short ushort8v __attribute__((ext_vector_type(8)));
typedef unsigned short ushort4v __attribute__((ext_vector_type(4)));

static __device__ __forceinline__ float bf2f(unsigned short u) {
  return __uint_as_float(((unsigned int)u) << 16);
}
static __device__ __forceinline__ unsigned short f2bf(float f) {  // RNE
  unsigned int u = __float_as_uint(f);
  return (unsigned short)((u + 0x7FFFu + ((u >> 16) & 1u)) >> 16);
}
static __device__ __forceinline__ float fsig(float x) {
  return 1.f / (1.f + __expf(-x));
}
static __device__ __forceinline__ float ftanh(float x) {
  return 1.f - 2.f / (__expf(2.f * x) + 1.f);
}
// swizzled column (in shorts) for logical (row, col) in a 1024-wide row
static __device__ __forceinline__ int swzcol(int row, int col) {
  int ch = col >> 3;
  int cs = (ch & ~7) | ((ch ^ row) & 7);
  return cs * 8 + (col & 7);
}
static __device__ __forceinline__ void gld_lds16(const void* g, void* l) {
  __builtin_amdgcn_global_load_lds(
      (const __attribute__((address_space(1))) unsigned int*)g,
      (__attribute__((address_space(3))) unsigned int*)l, 16, 0, 0);
}

// ---------------- weight pre-convert: 4x Wih fp32->bf16, bias sums ----------
// w1f/w1b written SWIZZLED; w2f/w2b linear.
__global__ __launch_bounds__(256) void cvt_w_kernel(
    const float* __restrict__ w1f, const float* __restrict__ w1b,
    const float* __restrict__ w2f, const float* __restrict__ w2b,
    const float* __restrict__ b1fi, const float* __restrict__ b1fh,
    const float* __restrict__ b1bi, const float* __restrict__ b1bh,
    const float* __restrict__ b2fi, const float* __restrict__ b2fh,
    const float* __restrict__ b2bi, const float* __restrict__ b2bh,
    unsigned short* __restrict__ d1f, unsigned short* __restrict__ d1b,
    unsigned short* __restrict__ d2f, unsigned short* __restrict__ d2b,
    float* __restrict__ bs)
{
  const int bid = blockIdx.x, tid = threadIdx.x;
  if (bid < 1280) {
    int idx = (bid * 256 + tid) * 4;
    const float* src;
    unsigned short* dst;
    int off;
    bool swz;
    if (idx < 524288)        { src = w1f; dst = d1f; off = idx; swz = true; }
    else if (idx < 1048576)  { src = w1b; dst = d1b; off = idx - 524288; swz = true; }
    else if (idx < 1179648)  { src = w2f; dst = d2f; off = idx - 1048576; swz = false; }
    else                     { src = w2b; dst = d2b; off = idx - 1179648; swz = false; }
    float4 f = *(const float4*)(src + off);
    ushort4v v;
    v[0] = f2bf(f.x); v[1] = f2bf(f.y); v[2] = f2bf(f.z); v[3] = f2bf(f.w);
    if (swz) {
      int row = off >> 10, col = off & 1023;
      *(ushort4v*)(dst + ((size_t)row << 10) + swzcol(row, col)) = v;
    } else {
      *(ushort4v*)(dst + off) = v;
    }
  } else {
    int bidx = (bid - 1280) * 256 + tid;   // 0..2047
    int which = bidx >> 9, col = bidx & 511;
    float v;
    if (which == 0)      v = b1fi[col] + b1fh[col];
    else if (which == 1) v = b1bi[col] + b1bh[col];
    else if (which == 2) v = b2fi[col] + b2fh[col];
    else                 v = b2bi[col] + b2bh[col];
    bs[bidx] = v;
  }
}

// ---------------- MFMA attention (r11 winner; g writes swizzled) --------
__global__ __launch_bounds__(256) void attn_kernel(
    const float* __restrict__ c, const float* __restrict__ q,
    const float* __restrict__ wc, const float* __restrict__ bc,
    const float* __restrict__ wq, const float* __restrict__ bq,
    const float* __restrict__ wcq, const float* __restrict__ bcq,
    const float* __restrict__ W0, const float* __restrict__ W1,
    __hip_bfloat16* __restrict__ g, float* __restrict__ smax,
    float* __restrict__ gz0, float* __restrict__ gz1)
{
  __shared__ unsigned short cbf[128][264];  // c bf16 (A for S; cv in epilogue)
  __shared__ unsigned short qhb[64][264];   // qhat bf16 j-major (B for S)
  __shared__ unsigned short qtb[256][72];   // q bf16 d-major (B for c2q)
  __shared__ unsigned short Pbuf[4][16][72];// per-wave P transpose (A for c2q)
  __shared__ float qwqs[64];
  __shared__ float qwp[4][64];
  const int b = blockIdx.x, tid = threadIdx.x;
  const int wave = tid >> 6, lane = tid & 63;
  const int t0 = blockIdx.y * 128;
  unsigned short* gbase = (unsigned short*)g;

  #pragma unroll
  for (int i = 0; i < 16; ++i) {
    int idx = tid + i * 256;               // 4096 float4
    int j = idx >> 6, d4 = (idx & 63) * 4;
    float4 v = *(const float4*)&q[((size_t)b * 64 + j) * 256 + d4];
    float4 w4 = *(const float4*)&wcq[d4];
    float4 c4 = *(const float4*)&wc[d4];
    qhb[j][d4 + 0] = f2bf(v.x * w4.x + c4.x);
    qhb[j][d4 + 1] = f2bf(v.y * w4.y + c4.y);
    qhb[j][d4 + 2] = f2bf(v.z * w4.z + c4.z);
    qhb[j][d4 + 3] = f2bf(v.w * w4.w + c4.w);
    qtb[d4 + 0][j] = f2bf(v.x);
    qtb[d4 + 1][j] = f2bf(v.y);
    qtb[d4 + 2][j] = f2bf(v.z);
    qtb[d4 + 3][j] = f2bf(v.w);
  }
  #pragma unroll
  for (int i = 0; i < 32; ++i) {
    int idx = tid + i * 256;               // 8192 float4
    int r = idx >> 6, d4 = (idx & 63) * 4;
    float4 v = *(const float4*)&c[((size_t)b * 512 + t0 + r) * 256 + d4];
    ushort4v u;
    u[0] = f2bf(v.x); u[1] = f2bf(v.y); u[2] = f2bf(v.z); u[3] = f2bf(v.w);
    *(ushort4v*)&cbf[r][d4] = u;
    *(ushort4v*)&gbase[((size_t)b * 512 + t0 + r) * 1024 + swzcol(r, d4)] = u;
  }
  __syncthreads();
  {
    float s = 0.f;
    for (int dd = 0; dd < 64; ++dd) {
      int d = wave * 64 + dd;
      s += bf2f(qtb[d][lane]) * wq[d];
    }
    qwp[wave][lane] = s;
  }
  __syncthreads();
  if (tid < 64) qwqs[tid] = qwp[0][tid] + qwp[1][tid] + qwp[2][tid] + qwp[3][tid] + bq[0];
  __syncthreads();

  const int cl = lane & 15, kg = lane >> 4;
  const float sbias = bc[0] + bcq[0];

  #pragma unroll
  for (int half = 0; half < 2; ++half) {
    const int tt = wave + half * 4;
    const int rowb = tt * 16;
    f32x4 acc[4] = {};
    #pragma unroll
    for (int kt = 0; kt < 8; ++kt) {
      short8v a = *(const short8v*)&cbf[rowb + cl][kt * 32 + kg * 8];
      #pragma unroll
      for (int jt = 0; jt < 4; ++jt) {
        short8v bq_ = *(const short8v*)&qhb[jt * 16 + cl][kt * 32 + kg * 8];
        acc[jt] = __builtin_amdgcn_mfma_f32_16x16x32_bf16(a, bq_, acc[jt], 0, 0, 0);
      }
    }
    #pragma unroll
    for (int jt = 0; jt < 4; ++jt) {
      float qadd = qwqs[jt * 16 + cl] + sbias;
      #pragma unroll
      for (int r = 0; r < 4; ++r) acc[jt][r] += qadd;
    }
    f32x4 mx = acc[0];
    #pragma unroll
    for (int jt = 1; jt < 4; ++jt)
      #pragma unroll
      for (int r = 0; r < 4; ++r) mx[r] = fmaxf(mx[r], acc[jt][r]);
    #pragma unroll
    for (int off = 1; off < 16; off <<= 1)
      #pragma unroll
      for (int r = 0; r < 4; ++r) mx[r] = fmaxf(mx[r], __shfl_xor(mx[r], off));
    f32x4 se = {0.f, 0.f, 0.f, 0.f};
    #pragma unroll
    for (int jt = 0; jt < 4; ++jt)
      #pragma unroll
      for (int r = 0; r < 4; ++r) {
        acc[jt][r] = __expf(acc[jt][r] - mx[r]);
        se[r] += acc[jt][r];
      }
    #pragma unroll
    for (int off = 1; off < 16; off <<= 1)
      #pragma unroll
      for (int r = 0; r < 4; ++r) se[r] += __shfl_xor(se[r], off);
    f32x4 inv;
    #pragma unroll
    for (int r = 0; r < 4; ++r) inv[r] = 1.f / se[r];
    #pragma unroll
    for (int jt = 0; jt < 4; ++jt)
      #pragma unroll
      for (int r = 0; r < 4; ++r)
        Pbuf[wave][4 * kg + r][jt * 16 + cl] = f2bf(acc[jt][r] * inv[r]);
    if (cl == 0) {
      #pragma unroll
      for (int r = 0; r < 4; ++r)
        smax[(size_t)b * 512 + t0 + rowb + 4 * kg + r] = mx[r];
    }
    f32x4 gz0p = {0.f, 0.f, 0.f, 0.f}, gz1p = {0.f, 0.f, 0.f, 0.f};
    for (int dt = 0; dt < 16; ++dt) {
      f32x4 ca = {0.f, 0.f, 0.f, 0.f};
      #pragma unroll
      for (int kt = 0; kt < 2; ++kt) {
        short8v pa = *(const short8v*)&Pbuf[wave][cl][kt * 32 + kg * 8];
        short8v qb_ = *(const short8v*)&qtb[dt * 16 + cl][kt * 32 + kg * 8];
        ca = __builtin_amdgcn_mfma_f32_16x16x32_bf16(pa, qb_, ca, 0, 0, 0);
      }
      int d = dt * 16 + cl;
      float w0a = W0[d], w0b_ = W0[256 + d], w0c2 = W0[512 + d];
      float w1a = W1[d], w1b2 = W1[256 + d], w1c2 = W1[512 + d];
      #pragma unroll
      for (int r = 0; r < 4; ++r) {
        int rloc = rowb + 4 * kg + r;
        float cv = bf2f(cbf[rloc][d]);
        float av = ca[r];
        float pr = cv * av;
        size_t gr = ((size_t)b * 512 + t0 + rloc) * 1024;
        gbase[gr + swzcol(rloc, 256 + d)] = f2bf(av);
        gbase[gr + swzcol(rloc, 512 + d)] = f2bf(pr);
        gz0p[r] += cv * w0a + av * w0b_ + pr * w0c2;
        gz1p[r] += cv * w1a + av * w1b2 + pr * w1c2;
      }
    }
    #pragma unroll
    for (int off = 1; off < 16; off <<= 1)
      #pragma unroll
      for (int r = 0; r < 4; ++r) {
        gz0p[r] += __shfl_xor(gz0p[r], off);
        gz1p[r] += __shfl_xor(gz1p[r], off);
      }
    if (cl == 0) {
      #pragma unroll
      for (int r = 0; r < 4; ++r) {
        size_t rw = (size_t)b * 512 + t0 + rowb + 4 * kg + r;
        gz0[rw] = gz0p[r];
        gz1[rw] = gz1p[r];
      }
    }
  }
}

// ---------------- b_att softmax over t, q2c, g[768:1024] (swizzled), gz tail ----
__global__ __launch_bounds__(256) void batt_kernel(
    const float* __restrict__ c, const float* __restrict__ smax,
    const float* __restrict__ W0, const float* __restrict__ W1,
    __hip_bfloat16* __restrict__ g,
    float* __restrict__ gz0, float* __restrict__ gz1)
{
  __shared__ float sm[512];
  __shared__ float red[4], red2[4];
  __shared__ float q2c_s[256];
  const int b = blockIdx.x, tid = threadIdx.x;
  float v0 = smax[(size_t)b * 512 + tid];
  float v1 = smax[(size_t)b * 512 + tid + 256];
  float m = fmaxf(v0, v1);
  #pragma unroll
  for (int off = 32; off; off >>= 1) m = fmaxf(m, __shfl_xor(m, off));
  if ((tid & 63) == 0) red[tid >> 6] = m;
  __syncthreads();
  float M = fmaxf(fmaxf(red[0], red[1]), fmaxf(red[2], red[3]));
  float e0 = expf(v0 - M), e1 = expf(v1 - M);
  float ssum = e0 + e1;
  #pragma unroll
  for (int off = 32; off; off >>= 1) ssum += __shfl_xor(ssum, off);
  if ((tid & 63) == 0) red2[tid >> 6] = ssum;
  __syncthreads();
  float S = red2[0] + red2[1] + red2[2] + red2[3];
  sm[tid] = e0 / S;
  sm[tid + 256] = e1 / S;
  __syncthreads();
  float acc = 0.f;
  #pragma unroll 8
  for (int t = 0; t < 512; ++t) acc += sm[t] * c[((size_t)b * 512 + t) * 256 + tid];
  q2c_s[tid] = acc;
  __syncthreads();
  const int wave = tid >> 6, lane = tid & 63;
  float qv[4], w0c[4], w1c[4];
  #pragma unroll
  for (int r = 0; r < 4; ++r) {
    int d = lane + 64 * r;
    qv[r]  = q2c_s[d];
    w0c[r] = W0[768 + d];
    w1c[r] = W1[768 + d];
  }
  for (int t = wave; t < 512; t += 4) {
    size_t row = (size_t)b * 512 + t;
    float s0 = 0.f, s1 = 0.f;
    #pragma unroll
    for (int r = 0; r < 4; ++r) {
      int d = lane + 64 * r;
      float v = c[row * 256 + d];
      float gv = v * qv[r];
      g[row * 1024 + swzcol(t, 768 + d)] = __float2bfloat16(gv);
      s0 += gv * w0c[r];
      s1 += gv * w1c[r];
    }
    #pragma unroll
    for (int off = 32; off; off >>= 1) {
      s0 += __shfl_xor(s0, off);
      s1 += __shfl_xor(s1, off);
    }
    if (lane == 0) { gz0[row] += s0; gz1[row] += s1; }
  }
}

// ---------------- gemm1: pre = g_swz @ W_swz^T + bs ----------------------------
// r15: double-buffered LDS + T3-minimum pipeline. Per K-tile: issue next
// tile's global_load_lds BEFORE computing current tile; ONE barrier per tile
// (syncthreads drains vmcnt -> next tile's stage landed + this tile's reads
// done before its buffer is restaged). Loads overlap fully with MFMA.
// LDS 64KB -> 2 blocks/CU.
__global__ __launch_bounds__(256) void gemm1_kernel(
    const unsigned short* __restrict__ X,
    const unsigned short* __restrict__ Wf, const unsigned short* __restrict__ Wb,
    const float* __restrict__ bsf, const float* __restrict__ bsb,
    __hip_bfloat16* __restrict__ Yf, __hip_bfloat16* __restrict__ Yb)
{
  __shared__ unsigned short Xs[2][128 * 64];
  __shared__ unsigned short Ws[2][128 * 64];
  const unsigned short* W = blockIdx.z ? Wb : Wf;
  const float* bs = blockIdx.z ? bsb : bsf;
  __hip_bfloat16* Y = blockIdx.z ? Yb : Yf;
  const int tid = threadIdx.x;
  const int m0 = blockIdx.x * 128, n0 = blockIdx.y * 128;
  const int lane = tid & 63, wave = tid >> 6;
  const int wr = wave >> 1, wc = wave & 1;
  const int frow = lane & 15, kg = lane >> 4;
  const int r7 = frow & 7;
  const int cid_l = wave * 64 + lane;

  // stage K-tile (kt element offset) into buffer bufi
#define STAGE(KT, BUFI)                                                      \
  {                                                                          \
    _Pragma("unroll")                                                        \
    for (int i = 0; i < 4; ++i) {                                            \
      int cb = i * 256 + wave * 64;                                          \
      int cid = i * 256 + cid_l;                                             \
      int row = cid >> 3, ch = cid & 7;                                      \
      gld_lds16(X + (size_t)(m0 + row) * 1024 + (KT) + ch * 8,               \
                &Xs[BUFI][cb * 8]);                                          \
      gld_lds16(W + (size_t)(n0 + row) * 1024 + (KT) + ch * 8,               \
                &Ws[BUFI][cb * 8]);                                          \
    }                                                                        \
  }

  f32x4 acc[4][4] = {};
  STAGE(0, 0)
  __syncthreads();
  for (int t = 0; t < 16; ++t) {
    const int buf = t & 1;
    if (t < 15) STAGE((t + 1) * 64, buf ^ 1)
    #pragma unroll
    for (int kk = 0; kk < 64; kk += 32) {
      const int pc = (((kk >> 3) + kg) ^ r7) * 8;
      short8v a[4], bfr[4];
      #pragma unroll
      for (int i = 0; i < 4; ++i)
        a[i] = *(const short8v*)&Xs[buf][(wr * 64 + i * 16 + frow) * 64 + pc];
      #pragma unroll
      for (int j = 0; j < 4; ++j)
        bfr[j] = *(const short8v*)&Ws[buf][(wc * 64 + j * 16 + frow) * 64 + pc];
      #pragma unroll
      for (int i = 0; i < 4; ++i)
        #pragma unroll
        for (int j = 0; j < 4; ++j)
          acc[i][j] = __builtin_amdgcn_mfma_f32_16x16x32_bf16(a[i], bfr[j], acc[i][j], 0, 0, 0);
    }
    __syncthreads();
  }
#undef STAGE
  const int r0 = kg * 4;
  #pragma unroll
  for (int j = 0; j < 4; ++j) {
    int col = n0 + wc * 64 + j * 16 + frow;
    int colp = (col & 127) * 4 + (col >> 7);
    float bsum = bs[col];
    #pragma unroll
    for (int i = 0; i < 4; ++i) {
      int rowb = m0 + wr * 64 + i * 16 + r0;
      #pragma unroll
      for (int r = 0; r < 4; ++r)
        Y[(size_t)(rowb + r) * 512 + colp] = __float2bfloat16(acc[i][j][r] + bsum);
    }
  }
}

// ---------------- MFMA GEMM (layer 2, linear W/m; unchanged) ------
__global__ __launch_bounds__(256) void gemm_mfma_kernel(
    const __hip_bfloat16* __restrict__ Xg,
    const unsigned short* __restrict__ Wf, const unsigned short* __restrict__ Wb,
    const float* __restrict__ bsf, const float* __restrict__ bsb,
    __hip_bfloat16* __restrict__ Yf, __hip_bfloat16* __restrict__ Yb, int K)
{
  __shared__ unsigned short Xs[128 * 72];
  __shared__ unsigned short Ws[128 * 72];
  const unsigned short* X = (const unsigned short*)Xg;
  const unsigned short* W = blockIdx.z ? Wb : Wf;
  const float* bs = blockIdx.z ? bsb : bsf;
  __hip_bfloat16* Y = blockIdx.z ? Yb : Yf;
  const int tid = threadIdx.x;
  const int m0 = blockIdx.x * 128, n0 = blockIdx.y * 128;
  const int lane = tid & 63, wave = tid >> 6;
  const int wr = wave >> 1, wc = wave & 1;
  const int frow = lane & 15, fk = (lane >> 4) * 8;

  f32x4 acc[4][4] = {};
  for (int kt = 0; kt < K; kt += 64) {
    #pragma unroll
    for (int i = 0; i < 4; ++i) {
      int cidx = tid + 256 * i;
      int row = cidx >> 3, kc = cidx & 7;
      *(ushort8v*)&Xs[row * 72 + kc * 8] =
          *(const ushort8v*)&X[(size_t)(m0 + row) * K + kt + kc * 8];
      *(ushort8v*)&Ws[row * 72 + kc * 8] =
          *(const ushort8v*)&W[(size_t)(n0 + row) * K + kt + kc * 8];
    }
    __syncthreads();
    #pragma unroll
    for (int kk = 0; kk < 64; kk += 32) {
      short8v a[4], bfr[4];
      #pragma unroll
      for (int i = 0; i < 4; ++i)
        a[i] = *(const short8v*)&Xs[(wr * 64 + i * 16 + frow) * 72 + kk + fk];
      #pragma unroll
      for (int j = 0; j < 4; ++j)
        bfr[j] = *(const short8v*)&Ws[(wc * 64 + j * 16 + frow) * 72 + kk + fk];
      #pragma unroll
      for (int i = 0; i < 4; ++i)
        #pragma unroll
        for (int j = 0; j < 4; ++j)
          acc[i][j] = __builtin_amdgcn_mfma_f32_16x16x32_bf16(a[i], bfr[j], acc[i][j], 0, 0, 0);
    }
    __syncthreads();
  }
  const int r0 = (lane >> 4) * 4;
  #pragma unroll
  for (int j = 0; j < 4; ++j) {
    int col = n0 + wc * 64 + j * 16 + (lane & 15);
    int colp = (col & 127) * 4 + (col >> 7);
    float bsum = bs[col];
    #pragma unroll
    for (int i = 0; i < 4; ++i) {
      int rowb = m0 + wr * 64 + i * 16 + r0;
      #pragma unroll
      for (int r = 0; r < 4; ++r)
        Y[(size_t)(rowb + r) * 512 + colp] = __float2bfloat16(acc[i][j][r] + bsum);
    }
  }
}

// ---------------- LSTM recurrence via MFMA, 8-step chunked I/O (floored) ------
// Structural floor established r4-r14: step ~1530cy = 620cy MFMA-issue floor +
// serial chain (ds_read -> MFMA x4 -> exp -> cst -> tanh -> write -> barrier).
// 512 thr / 8 waves is the best of 7 variants. Do not touch.
__global__ __launch_bounds__(512, 2) void lstm_kernel(
    const __hip_bfloat16* __restrict__ pre_f, const __hip_bfloat16* __restrict__ pre_b,
    const float* __restrict__ Whh_f, const float* __restrict__ Whh_b,
    __hip_bfloat16* __restrict__ out)
{
  const int b = blockIdx.x, dir = blockIdx.y;
  const unsigned short* __restrict__ pre =
      (const unsigned short*)(dir ? pre_b : pre_f);
  const float* __restrict__ Whh = dir ? Whh_b : Whh_f;
  const int off = dir ? 128 : 0;
  const int tid = threadIdx.x;
  const int wave = tid >> 6, lane = tid & 63;
  const int cl = lane & 15;            // col / cell-within-wave
  const int kg = lane >> 4;            // k-group 0..3
  const int cell = wave * 16 + cl;     // 0..127

#define LOAD_BF(Q, T, DST)                                            \
  {                                                                   \
    const float* wp = Whh + (size_t)(Q * 128 + cell) * 128 + T * 32 + kg * 8; \
    float4 f0 = *(const float4*)wp;                                   \
    float4 f1 = *(const float4*)(wp + 4);                             \
    DST[0] = (short)f2bf(f0.x); DST[1] = (short)f2bf(f0.y);           \
    DST[2] = (short)f2bf(f0.z); DST[3] = (short)f2bf(f0.w);           \
    DST[4] = (short)f2bf(f1.x); DST[5] = (short)f2bf(f1.y);           \
    DST[6] = (short)f2bf(f1.z); DST[7] = (short)f2bf(f1.w);           \
    asm volatile("" : "+v"(DST));                                     \
  }
  short8v bf00, bf01, bf02, bf03, bf10, bf11, bf12, bf13;
  short8v bf20, bf21, bf22, bf23, bf30, bf31, bf32, bf33;
  LOAD_BF(0, 0, bf00) LOAD_BF(0, 1, bf01) LOAD_BF(0, 2, bf02) LOAD_BF(0, 3, bf03)
  LOAD_BF(1, 0, bf10) LOAD_BF(1, 1, bf11) LOAD_BF(1, 2, bf12) LOAD_BF(1, 3, bf13)
  LOAD_BF(2, 0, bf20) LOAD_BF(2, 1, bf21) LOAD_BF(2, 2, bf22) LOAD_BF(2, 3, bf23)
  LOAD_BF(3, 0, bf30) LOAD_BF(3, 1, bf31) LOAD_BF(3, 2, bf32) LOAD_BF(3, 3, bf33)
#undef LOAD_BF

  __shared__ unsigned short hbuf[2][128];
  if (tid < 128) { hbuf[0][tid] = 0; hbuf[1][tid] = 0; }
  __syncthreads();

  const size_t base = (size_t)b * 512;
  const int tstep = dir ? -1 : 1;
  const int t0 = dir ? 511 : 0;
  const unsigned short* prow = pre + base * 512 + cell * 4;
  unsigned short* orow = (unsigned short*)out + base * 256 + off + cell;

  int cur = 0;
  float cst = 0.f;
  f32x4 acc0 = {0.f, 0.f, 0.f, 0.f};
  f32x4 acc1 = acc0, acc2 = acc0, acc3 = acc0;

#define LSTM_STEP(P, HOUT)                                                  \
  {                                                                         \
    const unsigned short* hb = hbuf[cur];                                   \
    short8v a0 = *(const short8v*)(hb +  0 + kg * 8);                       \
    short8v a1 = *(const short8v*)(hb + 32 + kg * 8);                       \
    short8v a2 = *(const short8v*)(hb + 64 + kg * 8);                       \
    short8v a3 = *(const short8v*)(hb + 96 + kg * 8);                       \
    acc0[0] = bf2f(P[0]); acc1[0] = bf2f(P[1]);                             \
    acc2[0] = bf2f(P[2]); acc3[0] = bf2f(P[3]);                             \
    acc0 = __builtin_amdgcn_mfma_f32_16x16x32_bf16(a0, bf00, acc0, 0, 0, 0);\
    acc1 = __builtin_amdgcn_mfma_f32_16x16x32_bf16(a0, bf10, acc1, 0, 0, 0);\
    acc2 = __builtin_amdgcn_mfma_f32_16x16x32_bf16(a0, bf20, acc2, 0, 0, 0);\
    acc3 = __builtin_amdgcn_mfma_f32_16x16x32_bf16(a0, bf30, acc3, 0, 0, 0);\
    acc0 = __builtin_amdgcn_mfma_f32_16x16x32_bf16(a1, bf01, acc0, 0, 0, 0);\
    acc1 = __builtin_amdgcn_mfma_f32_16x16x32_bf16(a1, bf11, acc1, 0, 0, 0);\
    acc2 = __builtin_amdgcn_mfma_f32_16x16x32_bf16(a1, bf21, acc2, 0, 0, 0);\
    acc3 = __builtin_amdgcn_mfma_f32_16x16x32_bf16(a1, bf31, acc3, 0, 0, 0);\
    acc0 = __builtin_amdgcn_mfma_f32_16x16x32_bf16(a2, bf02, acc0, 0, 0, 0);\
    acc1 = __builtin_amdgcn_mfma_f32_16x16x32_bf16(a2, bf12, acc1, 0, 0, 0);\
    acc2 = __builtin_amdgcn_mfma_f32_16x16x32_bf16(a2, bf22, acc2, 0, 0, 0);\
    acc3 = __builtin_amdgcn_mfma_f32_16x16x32_bf16(a2, bf32, acc3, 0, 0, 0);\
    acc0 = __builtin_amdgcn_mfma_f32_16x16x32_bf16(a3, bf03, acc0, 0, 0, 0);\
    acc1 = __builtin_amdgcn_mfma_f32_16x16x32_bf16(a3, bf13, acc1, 0, 0, 0);\
    acc2 = __builtin_amdgcn_mfma_f32_16x16x32_bf16(a3, bf23, acc2, 0, 0, 0);\
    acc3 = __builtin_amdgcn_mfma_f32_16x16x32_bf16(a3, bf33, acc3, 0, 0, 0);\
    float gi_ = fsig(acc0[0]);                                              \
    float gf_ = fsig(acc1[0]);                                              \
    float gg_ = ftanh(acc2[0]);                                             \
    float go_ = fsig(acc3[0]);                                              \
    cst = gf_ * cst + gi_ * gg_;                                            \
    float hv = go_ * ftanh(cst);                                            \
    HOUT = f2bf(hv);                                                        \
    if (lane < 16) hbuf[cur ^ 1][cell] = HOUT;                              \
    asm volatile("s_waitcnt lgkmcnt(0)" ::: "memory");                      \
    __builtin_amdgcn_s_barrier();                                           \
    cur ^= 1;                                                               \
  }

  for (int chunk = 0; chunk < 64; ++chunk) {
    const int tb = t0 + chunk * 8 * tstep;
    ushort4v p0 = *(const ushort4v*)(prow + (size_t)(tb)             * 512);
    ushort4v p1 = *(const ushort4v*)(prow + (size_t)(tb + 1 * tstep) * 512);
    ushort4v p2 = *(const ushort4v*)(prow + (size_t)(tb + 2 * tstep) * 512);
    ushort4v p3 = *(const ushort4v*)(prow + (size_t)(tb + 3 * tstep) * 512);
    ushort4v p4 = *(const ushort4v*)(prow + (size_t)(tb + 4 * tstep) * 512);
    ushort4v p5 = *(const ushort4v*)(prow + (size_t)(tb + 5 * tstep) * 512);
    ushort4v p6 = *(const ushort4v*)(prow + (size_t)(tb + 6 * tstep) * 512);
    ushort4v p7 = *(const ushort4v*)(prow + (size_t)(tb + 7 * tstep) * 512);
    unsigned short h0, h1, h2, h3, h4, h5, h6, h7;
    LSTM_STEP(p0, h0)
    LSTM_STEP(p1, h1)
    LSTM_STEP(p2, h2)
    LSTM_STEP(p3, h3)
    LSTM_STEP(p4, h4)
    LSTM_STEP(p5, h5)
    LSTM_STEP(p6, h6)
    LSTM_STEP(p7, h7)
    if (lane < 16) {
      orow[(size_t)(tb)             * 256] = h0;
      orow[(size_t)(tb + 1 * tstep) * 256] = h1;
      orow[(size_t)(tb + 2 * tstep) * 256] = h2;
      orow[(size_t)(tb + 3 * tstep) * 256] = h3;
      orow[(size_t)(tb + 4 * tstep) * 256] = h4;
      orow[(size_t)(tb + 5 * tstep) * 256] = h5;
      orow[(size_t)(tb + 6 * tstep) * 256] = h6;
      orow[(size_t)(tb + 7 * tstep) * 256] = h7;
    }
  }
#undef LSTM_STEP
}

// ---------------- logits: z[row] = gz[row] + m_row(bf16) . W[1024:1280] + bias ----
__global__ __launch_bounds__(256) void logits_kernel(
    const __hip_bfloat16* __restrict__ m, const float* __restrict__ W,
    const float* __restrict__ bias, const float* __restrict__ gz,
    float* __restrict__ z)
{
  const int row = blockIdx.x * 4 + (threadIdx.x >> 6);
  const int lane = threadIdx.x & 63;
  const unsigned short* mrow = (const unsigned short*)m + (size_t)row * 256;
  float acc = 0.f;
  #pragma unroll
  for (int i = 0; i < 4; ++i) acc += bf2f(mrow[lane + 64 * i]) * W[1024 + lane + 64 * i];
  #pragma unroll
  for (int off = 32; off; off >>= 1) acc += __shfl_xor(acc, off);
  if (lane == 0) z[row] = acc + gz[row] + bias[0];
}

// ---------------- softmax over t ----------------
__global__ __launch_bounds__(512) void softmax_t_kernel(
    const float* __restrict__ z, float* __restrict__ p)
{
  const int b = blockIdx.x, t = threadIdx.x;
  __shared__ float red[8], red2[8];
  float v = z[(size_t)b * 512 + t];
  float m = v;
  #pragma unroll
  for (int off = 32; off; off >>= 1) m = fmaxf(m, __shfl_xor(m, off));
  if ((t & 63) == 0) red[t >> 6] = m;
  __syncthreads();
  float M = red[0];
  #pragma unroll
  for (int i = 1; i < 8; ++i) M = fmaxf(M, red[i]);
  float e = expf(v - M);
  float s = e;
  #pragma unroll
  for (int off = 32; off; off >>= 1) s += __shfl_xor(s, off);
  if ((t & 63) == 0) red2[t >> 6] = s;
  __syncthreads();
  float S = red2[0];
  #pragma unroll
  for (int i = 1; i < 8; ++i) S += red2[i];
  p[(size_t)b * 512 + t] = e / S;
}

extern "C" void kernel_launch(void* const* d_in, const int* in_sizes, int n_in,
                              void* d_out, int out_size, void* d_ws, size_t ws_size,
                              hipStream_t stream)
{
  const float* c   = (const float*)d_in[0];
  const float* q   = (const float*)d_in[1];
  const float* wc  = (const float*)d_in[2];
  const float* bc  = (const float*)d_in[3];
  const float* wq  = (const float*)d_in[4];
  const float* bq  = (const float*)d_in[5];
  const float* wcq = (const float*)d_in[6];
  const float* bcq = (const float*)d_in[7];
  const float* l1f_Wih = (const float*)d_in[8];
  const float* l1f_Whh = (const float*)d_in[9];
  const float* l1f_bih = (const float*)d_in[10];
  const float* l1f_bhh = (const float*)d_in[11];
  const float* l1b_Wih = (const float*)d_in[12];
  const float* l1b_Whh = (const float*)d_in[13];
  const float* l1b_bih = (const float*)d_in[14];
  const float* l1b_bhh = (const float*)d_in[15];
  const float* l2f_Wih = (const float*)d_in[16];
  const float* l2f_Whh = (const float*)d_in[17];
  const float* l2f_bih = (const float*)d_in[18];
  const float* l2f_bhh = (const float*)d_in[19];
  const float* l2b_Wih = (const float*)d_in[20];
  const float* l2b_Whh = (const float*)d_in[21];
  const float* l2b_bih = (const float*)d_in[22];
  const float* l2b_bhh = (const float*)d_in[23];
  const float* W0 = (const float*)d_in[24];
  const float* b0 = (const float*)d_in[25];
  const float* W1 = (const float*)d_in[26];
  const float* b1 = (const float*)d_in[27];

  const size_t required = 137371648u;
  if (ws_size < required) return;

  char* wsb = (char*)d_ws;
  __hip_bfloat16* gbf = (__hip_bfloat16*)wsb;
  __hip_bfloat16* m   = (__hip_bfloat16*)wsb;
  __hip_bfloat16* m2  = (__hip_bfloat16*)(wsb + 33554432);
  __hip_bfloat16* pref = (__hip_bfloat16*)(wsb + 67108864);
  __hip_bfloat16* preb = (__hip_bfloat16*)(wsb + 100663296);
  float* gz0  = (float*)(wsb + 134217728);
  float* gz1  = gz0 + 32768;
  float* smax = gz1 + 32768;
  float* z    = smax + 32768;
  unsigned short* w1f = (unsigned short*)(wsb + 134742016);
  unsigned short* w1b = (unsigned short*)(wsb + 135790592);
  unsigned short* w2f = (unsigned short*)(wsb + 136839168);
  unsigned short* w2b = (unsigned short*)(wsb + 137101312);
  float* bs = (float*)(wsb + 137363456);
  float* p1 = (float*)d_out;
  float* p2 = p1 + 32768;

  cvt_w_kernel<<<1288, 256, 0, stream>>>(l1f_Wih, l1b_Wih, l2f_Wih, l2b_Wih,
                                         l1f_bih, l1f_bhh, l1b_bih, l1b_bhh,
                                         l2f_bih, l2f_bhh, l2b_bih, l2b_bhh,
                                         w1f, w1b, w2f, w2b, bs);
  attn_kernel<<<dim3(64, 4), 256, 0, stream>>>(c, q, wc, bc, wq, bq, wcq, bcq,
                                               W0, W1, gbf, smax, gz0, gz1);
  batt_kernel<<<64, 256, 0, stream>>>(c, smax, W0, W1, gbf, gz0, gz1);

  gemm1_kernel<<<dim3(256, 4, 2), 256, 0, stream>>>(
      (const unsigned short*)gbf, w1f, w1b, bs, bs + 512, pref, preb);
  lstm_kernel<<<dim3(64, 2), 512, 0, stream>>>(pref, preb, l1f_Whh, l1b_Whh, m);

  logits_kernel<<<8192, 256, 0, stream>>>(m, W0, b0, gz0, z);
  softmax_t_kernel<<<64, 512, 0, stream>>>(z, p1);

  gemm_mfma_kernel<<<dim3(256, 4, 2), 256, 0, stream>>>(
      m, w2f, w2b, bs + 1024, bs + 1536, pref, preb, 256);
  lstm_kernel<<<dim3(64, 2), 512, 0, stream>>>(pref, preb, l2f_Whh, l2b_Whh, m2);

  logits_kernel<<<8192, 256, 0, stream>>>(m2, W1, b1, gz1, z);
  softmax_t_kernel<<<64, 512, 0, stream>>>(z, p2);
}